// Round 14
// baseline (1873.186 us; speedup 1.0000x reference)
//
#include <hip/hip_runtime.h>
#include <hip/hip_bf16.h>

#define N_NODES 50000
#define N_EDGES 600000
#define D 128
#define D2 256
#define NGRAPH 512
#define NTARGET 10
#define NSB 49   // scan blocks
#define NSLOT 32 // stat accumulation slots

static constexpr float MSG_EPS_F = 1e-7f;
static constexpr float BN_EPS_F  = 1e-5f;

typedef _Float16 half8 __attribute__((ext_vector_type(8)));
typedef _Float16 half4v __attribute__((ext_vector_type(4)));
typedef float f32x4 __attribute__((ext_vector_type(4)));
#define MFMA16(a, b, c) __builtin_amdgcn_mfma_f32_16x16x32_f16(a, b, c, 0, 0, 0)

// ---------------------------------------------------------------- encoder: h fp32 + hh fp16 (+ zero deg)
__global__ __launch_bounds__(256) void k_encode(
    const int* __restrict__ x, const int* __restrict__ aoff,
    const float* __restrict__ atab, float* __restrict__ h,
    _Float16* __restrict__ hh, int* __restrict__ deg) {
  int tid = blockIdx.x * 256 + threadIdx.x;
  if (tid < N_NODES) deg[tid] = 0;
  int n = tid >> 5, f4 = (tid & 31) << 2;
  if (n >= N_NODES) return;
  float4 acc = make_float4(0.f, 0.f, 0.f, 0.f);
#pragma unroll
  for (int i = 0; i < 9; ++i) {
    int row = x[n * 9 + i] + aoff[i];
    float4 v = *(const float4*)&atab[row * D + f4];
    acc.x += v.x; acc.y += v.y; acc.z += v.z; acc.w += v.w;
  }
  *(float4*)&h[(size_t)n * D + f4] = acc;
  half4v o = {(_Float16)acc.x, (_Float16)acc.y, (_Float16)acc.z, (_Float16)acc.w};
  *(half4v*)&hh[(size_t)n * D + f4] = o;
}

// ---------------------------------------------------------------- merged setup: packW + combo + gbounds + misc init
__global__ __launch_bounds__(256) void k_setup(
    const float* __restrict__ w1, const float* __restrict__ w2,
    _Float16* __restrict__ w1p, _Float16* __restrict__ w2p,
    const int* __restrict__ boff, const float* __restrict__ btab,
    _Float16* __restrict__ comboh, const int* __restrict__ batch,
    int* __restrict__ gstart, int* __restrict__ hist,
    _Float16* __restrict__ bncoefh) {
  int b = blockIdx.x, tid = threadIdx.x;
  if (b < 224) {            // weight pre-pack: 57344 threads
    int t = b * 256 + tid;
    if (t < 7 * 4096) {
      int lane = t & 63, ntAll = (t >> 6) & 15, kc = (t >> 10) & 3, l = t >> 12;
      int q = lane >> 4, c = ntAll * 16 + (lane & 15);
      int kbase = kc * 32 + q * 8;
      const float* W = w1 + (size_t)l * D * D2;
      half8 v;
#pragma unroll
      for (int j = 0; j < 8; ++j) v[j] = (_Float16)W[(size_t)(kbase + j) * D2 + c];
      *(half8*)&w1p[(size_t)t * 8] = v;
    } else {
      int u = t - 7 * 4096;
      int lane = u & 63, nt = (u >> 6) & 7, kcAll = (u >> 9) & 7, l = u >> 12;
      int q = lane >> 4, c = nt * 16 + (lane & 15);
      int kbase = kcAll * 32 + q * 8;
      const float* W = w2 + (size_t)l * D2 * D;
      half8 v;
#pragma unroll
      for (int j = 0; j < 8; ++j) v[j] = (_Float16)W[(size_t)(kbase + j) * D + c];
      *(half8*)&w2p[(size_t)u * 8] = v;
    }
  } else if (b < 254) {     // combo table: 60*128 threads
    int t = (b - 224) * 256 + tid;
    int c = t >> 7, f = t & 127;
    if (c < 60) {
      int a0 = c / 12, a1 = (c % 12) / 2, a2 = c % 2;
      comboh[c * D + f] = (_Float16)(btab[(boff[0] + a0) * D + f] +
                                     btab[(boff[1] + a1) * D + f] +
                                     btab[(boff[2] + a2) * D + f]);
    }
  } else if (b < 450) {     // graph bounds
    int n = (b - 254) * 256 + tid;
    if (n >= N_NODES) return;
    int b0 = batch[n];
    int b1 = (n + 1 < N_NODES) ? batch[n + 1] : NGRAPH;
    for (int bb = b0 + 1; bb <= b1; ++bb) gstart[bb] = n + 1;
    if (n == 0)
      for (int bb = 0; bb <= b0; ++bb) gstart[bb] = 0;
  } else {                  // misc: identity bncoef (layer 0), zero hist
    if (tid < 128) {
      bncoefh[tid] = (_Float16)1.f;
      bncoefh[128 + tid] = (_Float16)0.f;
    }
    if (tid < 64) hist[tid] = 0;
  }
}

// ---------------------------------------------------------------- CSR build
__global__ __launch_bounds__(256) void k_degree(
    const int* __restrict__ ei, int* __restrict__ deg) {
  int e = blockIdx.x * 256 + threadIdx.x;
  if (e >= N_EDGES) return;
  atomicAdd(&deg[ei[N_EDGES + e]], 1);
}

__global__ __launch_bounds__(1024) void k_scan1(
    const int* __restrict__ deg, int* __restrict__ excl,
    int* __restrict__ bsum, int* __restrict__ hist) {
  __shared__ int tmp[1024];
  __shared__ int lh[64];
  int t = threadIdx.x, i = blockIdx.x * 1024 + t;
  if (t < 64) lh[t] = 0;
  int v = (i < N_NODES) ? deg[i] : 0;
  tmp[t] = v;
  __syncthreads();
  if (i < N_NODES) atomicAdd(&lh[min(v, 63)], 1);
  for (int off = 1; off < 1024; off <<= 1) {
    int add = (t >= off) ? tmp[t - off] : 0;
    __syncthreads();
    tmp[t] += add;
    __syncthreads();
  }
  if (i < N_NODES) excl[i] = tmp[t] - v;
  if (t == 1023) bsum[blockIdx.x] = tmp[1023];
  __syncthreads();
  if (t < 64 && lh[t]) atomicAdd(&hist[t], lh[t]);
}

// merged: scan of block sums + scan of degree histogram
__global__ __launch_bounds__(64) void k_scan2(
    int* __restrict__ bsum, const int* __restrict__ hist,
    int* __restrict__ cursor2) {
  __shared__ int s[64], s2[64];
  int t = threadIdx.x;
  int v1 = (t < NSB) ? bsum[t] : 0;
  int v2 = hist[t];
  s[t] = v1; s2[t] = v2;
  __syncthreads();
  for (int off = 1; off < 64; off <<= 1) {
    int a1 = (t >= off) ? s[t - off] : 0;
    int a2 = (t >= off) ? s2[t - off] : 0;
    __syncthreads();
    s[t] += a1; s2[t] += a2;
    __syncthreads();
  }
  if (t < NSB) bsum[t] = s[t] - v1;
  cursor2[t] = s2[t] - v2;
}

// merged: rowptr/cursor finalize + degree-sorted permutation scatter
__global__ __launch_bounds__(256) void k_scan3(
    const int* __restrict__ excl, const int* __restrict__ bsum,
    const int* __restrict__ deg, int* __restrict__ cursor2,
    int* __restrict__ rowptr, int* __restrict__ cursor,
    int* __restrict__ perm) {
  __shared__ int lh[64], lbase[64];
  int tid = threadIdx.x;
  if (tid < 64) lh[tid] = 0;
  __syncthreads();
  int i = blockIdx.x * 256 + tid;
  int b = -1, lpos = 0;
  if (i < N_NODES) {
    int v = excl[i] + bsum[i >> 10];
    rowptr[i] = v;
    cursor[i] = v;
    b = min(deg[i], 63);
    lpos = atomicAdd(&lh[b], 1);
  }
  if (i == N_NODES) rowptr[N_NODES] = N_EDGES;
  __syncthreads();
  if (tid < 64 && lh[tid]) lbase[tid] = atomicAdd(&cursor2[tid], lh[tid]);
  __syncthreads();
  if (b >= 0) perm[lbase[b] + lpos] = i;
}

__global__ __launch_bounds__(256) void k_scatter(
    const int* __restrict__ ei, const int* __restrict__ eattr,
    int* __restrict__ cursor, int* __restrict__ payload) {
  int e = blockIdx.x * 256 + threadIdx.x;
  if (e >= N_EDGES) return;
  int src = ei[e], dst = ei[N_EDGES + e];
  int cid = eattr[e * 3 + 0] * 12 + eattr[e * 3 + 1] * 2 + eattr[e * 3 + 2];
  int pos = atomicAdd(&cursor[dst], 1);
  payload[pos] = (src << 6) | cid;
}

// ---------------------------------------------------------------- aggregation (packed fp16 vectors, BN folded, eps folded, degree-sorted)
__global__ __launch_bounds__(256) void k_aggrx(
    const _Float16* __restrict__ hh, const int* __restrict__ rowptr,
    const int* __restrict__ payload, const _Float16* __restrict__ comboh,
    const int* __restrict__ perm, const float* __restrict__ tptr, int l,
    const _Float16* __restrict__ bncoefh, float negcap,
    _Float16* __restrict__ xh) {
  int tid = blockIdx.x * 256 + threadIdx.x;
  int gi = tid >> 4, f8 = (tid & 15) << 3;
  if (gi >= N_NODES) return;
  int dst = perm[gi];
  float tv = tptr[l];
  half8 a8 = *(const half8*)&bncoefh[f8];
  half8 b8 = *(const half8*)&bncoefh[128 + f8];
  half8 cap8, zero8;
#pragma unroll
  for (int j = 0; j < 8; ++j) { cap8[j] = (_Float16)negcap; zero8[j] = (_Float16)0.f; }
  int s = rowptr[dst], e = rowptr[dst + 1];
  float den[8], S[8];
#pragma unroll
  for (int j = 0; j < 8; ++j) { den[j] = 0.f; S[j] = 0.f; }
  int i = s;
  for (; i + 1 < e; i += 2) {
    int p0 = payload[i], p1 = payload[i + 1];
    half8 h0 = *(const half8*)&hh[(size_t)(p0 >> 6) * D + f8];
    half8 h1 = *(const half8*)&hh[(size_t)(p1 >> 6) * D + f8];
    half8 c0 = *(const half8*)&comboh[(p0 & 63) * D + f8];
    half8 c1 = *(const half8*)&comboh[(p1 & 63) * D + f8];
    half8 r0 = __builtin_elementwise_max(h0 * a8 + b8, cap8);
    half8 m0 = __builtin_elementwise_max(r0 + c0, zero8);
    half8 r1 = __builtin_elementwise_max(h1 * a8 + b8, cap8);
    half8 m1 = __builtin_elementwise_max(r1 + c1, zero8);
#pragma unroll
    for (int j = 0; j < 8; ++j) {
      float mf0 = (float)m0[j], mf1 = (float)m1[j];
      float e0 = __expf(mf0 * tv), e1 = __expf(mf1 * tv);
      den[j] += e0 + e1;
      S[j] += mf0 * e0 + mf1 * e1;
    }
  }
  if (i < e) {
    int p0 = payload[i];
    half8 h0 = *(const half8*)&hh[(size_t)(p0 >> 6) * D + f8];
    half8 c0 = *(const half8*)&comboh[(p0 & 63) * D + f8];
    half8 r0 = __builtin_elementwise_max(h0 * a8 + b8, cap8);
    half8 m0 = __builtin_elementwise_max(r0 + c0, zero8);
#pragma unroll
    for (int j = 0; j < 8; ++j) {
      float mf0 = (float)m0[j];
      float e0 = __expf(mf0 * tv);
      den[j] += e0;
      S[j] += mf0 * e0;
    }
  }
  half8 hd = *(const half8*)&hh[(size_t)dst * D + f8];
  half8 rd = __builtin_elementwise_max(hd * a8 + b8, cap8);
  half8 o;
#pragma unroll
  for (int j = 0; j < 8; ++j)
    o[j] = (_Float16)((float)rd[j] + S[j] / (den[j] + 1e-16f) + MSG_EPS_F);
  *(half8*)&xh[(size_t)dst * D + f8] = o;
}

// ---------------------------------------------------------------- GEMM1 (MFMA fp16): z1h = fp16(xh @ W1 + b1); slotted stats
__global__ __launch_bounds__(256) void k_gemm1(
    const _Float16* __restrict__ xh, const _Float16* __restrict__ w1p,
    const float* __restrict__ b1, _Float16* __restrict__ z1h,
    float* __restrict__ stat1s) {
  __shared__ __align__(16) _Float16 Af[512 * 8];   // 8 KB
  int tid = threadIdx.x;
  int row0 = blockIdx.x * 32;
  int slot = blockIdx.x & (NSLOT - 1);

#pragma unroll
  for (int s0 = 0; s0 < 2; ++s0) {
    int s = s0 * 256 + tid;
    int kc = s >> 7, mt = (s >> 6) & 1, l2 = s & 63;
    int row = row0 + mt * 16 + (l2 & 15);
    int kb = kc * 32 + ((l2 >> 4) << 3);
    half8 v;
    if (row < N_NODES) {
      v = *(const half8*)&xh[(size_t)row * D + kb];
    } else {
#pragma unroll
      for (int j = 0; j < 8; ++j) v[j] = (_Float16)0.f;
    }
    *(half8*)&Af[s * 8] = v;
  }
  __syncthreads();

  int wv = tid >> 6, ln = tid & 63;
  f32x4 acc[2][4];
#pragma unroll
  for (int i = 0; i < 2; ++i)
#pragma unroll
    for (int j = 0; j < 4; ++j) acc[i][j] = (f32x4){0.f, 0.f, 0.f, 0.f};

#pragma unroll
  for (int kc = 0; kc < 4; ++kc) {
    half8 a0 = *(half8*)&Af[((kc * 2 + 0) * 64 + ln) * 8];
    half8 a1 = *(half8*)&Af[((kc * 2 + 1) * 64 + ln) * 8];
#pragma unroll
    for (int nt = 0; nt < 4; ++nt) {
      int ntAll = wv * 4 + nt;
      half8 b = *(const half8*)&w1p[((size_t)(kc * 16 + ntAll) * 64 + ln) * 8];
      acc[0][nt] = MFMA16(a0, b, acc[0][nt]);
      acc[1][nt] = MFMA16(a1, b, acc[1][nt]);
    }
  }
  int lq = ln >> 4, lc = ln & 15;
  float cs[4], cq[4];
#pragma unroll
  for (int nt = 0; nt < 4; ++nt) { cs[nt] = 0.f; cq[nt] = 0.f; }
#pragma unroll
  for (int nt = 0; nt < 4; ++nt) {
    int col = (wv * 4 + nt) * 16 + lc;
    float bias = b1[col];
#pragma unroll
    for (int mt = 0; mt < 2; ++mt) {
      int rbase = row0 + mt * 16 + lq * 4;
#pragma unroll
      for (int rg = 0; rg < 4; ++rg) {
        int row = rbase + rg;
        if (row < N_NODES) {
          float z = acc[mt][nt][rg] + bias;
          z1h[(size_t)row * D2 + col] = (_Float16)z;
          cs[nt] += z; cq[nt] += z * z;
        }
      }
    }
  }
#pragma unroll
  for (int nt = 0; nt < 4; ++nt) {
    float v = cs[nt], q = cq[nt];
    v += __shfl_xor(v, 16); v += __shfl_xor(v, 32);
    q += __shfl_xor(q, 16); q += __shfl_xor(q, 32);
    if (lq == 0) {
      int col = (wv * 4 + nt) * 16 + lc;
      atomicAdd(&stat1s[slot * 512 + col], v);
      atomicAdd(&stat1s[slot * 512 + 256 + col], q);
    }
  }
}

// ---------------------------------------------------------------- GEMM2: h = relu(BN(z1)) @ W2 + b2 (+h); h fp32 + hh fp16 + next bncoef
__global__ __launch_bounds__(256) void k_gemm2(
    const _Float16* __restrict__ z1h, const float* __restrict__ stat1s,
    const float* __restrict__ g1, const float* __restrict__ bt1,
    const _Float16* __restrict__ w2p, const float* __restrict__ b2,
    float* __restrict__ h, _Float16* __restrict__ hh, int residual,
    float* __restrict__ statHs, const float* __restrict__ gnext,
    const float* __restrict__ btnext, _Float16* __restrict__ bncoefh,
    int computeNext, int* __restrict__ done) {
  __shared__ __align__(16) _Float16 Af[1024 * 8];   // 16 KB
  __shared__ float s1[512];
  const float invN = 1.0f / (float)N_NODES;
  int tid = threadIdx.x;
  int row0 = blockIdx.x * 32;
  int slot = blockIdx.x & (NSLOT - 1);

#pragma unroll
  for (int jj = 0; jj < 2; ++jj) {
    int j = jj * 256 + tid;
    float a = 0.f;
#pragma unroll
    for (int s = 0; s < NSLOT; ++s) a += stat1s[s * 512 + j];
    s1[j] = a;
  }
  __syncthreads();

#pragma unroll
  for (int s0 = 0; s0 < 4; ++s0) {
    int s = s0 * 256 + tid;
    int kcAll = s >> 7, mt = (s >> 6) & 1, l2 = s & 63;
    int row = row0 + mt * 16 + (l2 & 15);
    int kb = kcAll * 32 + ((l2 >> 4) << 3);
    half8 v;
    if (row < N_NODES) {
      half8 z = *(const half8*)&z1h[(size_t)row * D2 + kb];
#pragma unroll
      for (int j = 0; j < 8; ++j) {
        float mu = s1[kb + j] * invN;
        float isg = rsqrtf(s1[256 + kb + j] * invN - mu * mu + BN_EPS_F) * g1[kb + j];
        v[j] = (_Float16)fmaxf(((float)z[j] - mu) * isg + bt1[kb + j], 0.f);
      }
    } else {
#pragma unroll
      for (int j = 0; j < 8; ++j) v[j] = (_Float16)0.f;
    }
    *(half8*)&Af[s * 8] = v;
  }
  __syncthreads();

  int wv = tid >> 6, ln = tid & 63;
  f32x4 acc[2][2];
#pragma unroll
  for (int i = 0; i < 2; ++i)
#pragma unroll
    for (int j = 0; j < 2; ++j) acc[i][j] = (f32x4){0.f, 0.f, 0.f, 0.f};

#pragma unroll
  for (int kcAll = 0; kcAll < 8; ++kcAll) {
    half8 a0 = *(half8*)&Af[((kcAll * 2 + 0) * 64 + ln) * 8];
    half8 a1 = *(half8*)&Af[((kcAll * 2 + 1) * 64 + ln) * 8];
#pragma unroll
    for (int nt = 0; nt < 2; ++nt) {
      half8 b = *(const half8*)&w2p[((size_t)(kcAll * 8 + wv * 2 + nt) * 64 + ln) * 8];
      acc[0][nt] = MFMA16(a0, b, acc[0][nt]);
      acc[1][nt] = MFMA16(a1, b, acc[1][nt]);
    }
  }
  int lq = ln >> 4, lc = ln & 15;
  float cs[2], cq[2];
#pragma unroll
  for (int nt = 0; nt < 2; ++nt) { cs[nt] = 0.f; cq[nt] = 0.f; }
#pragma unroll
  for (int nt = 0; nt < 2; ++nt) {
    int col = (wv * 2 + nt) * 16 + lc;
    float bias = b2[col];
#pragma unroll
    for (int mt = 0; mt < 2; ++mt) {
      int rbase = row0 + mt * 16 + lq * 4;
#pragma unroll
      for (int rg = 0; rg < 4; ++rg) {
        int row = rbase + rg;
        if (row < N_NODES) {
          float v = acc[mt][nt][rg] + bias;
          if (residual) v += h[(size_t)row * D + col];
          h[(size_t)row * D + col] = v;
          hh[(size_t)row * D + col] = (_Float16)v;
          cs[nt] += v; cq[nt] += v * v;
        }
      }
    }
  }
#pragma unroll
  for (int nt = 0; nt < 2; ++nt) {
    float v = cs[nt], q = cq[nt];
    v += __shfl_xor(v, 16); v += __shfl_xor(v, 32);
    q += __shfl_xor(q, 16); q += __shfl_xor(q, 32);
    if (lq == 0) {
      int col = (wv * 2 + nt) * 16 + lc;
      atomicAdd(&statHs[slot * 256 + col], v);
      atomicAdd(&statHs[slot * 256 + 128 + col], q);
    }
  }
  // last-block: compute next layer's BN coefficients (saves a launch)
  if (computeNext) {
    __threadfence();
    __shared__ int amLast;
    if (tid == 0) amLast = (atomicAdd(done, 1) == (int)gridDim.x - 1) ? 1 : 0;
    __syncthreads();
    if (amLast) {
      if (tid == 0) *done = 0;
      __threadfence();
      if (tid < 128) {
        float s = 0.f, sq = 0.f;
#pragma unroll
        for (int sl = 0; sl < NSLOT; ++sl) {
          s  += atomicAdd(&statHs[sl * 256 + tid], 0.f);
          sq += atomicAdd(&statHs[sl * 256 + 128 + tid], 0.f);
        }
        float mu = s * invN, var = sq * invN - mu * mu;
        float isg = rsqrtf(var + BN_EPS_F) * gnext[tid];
        bncoefh[tid] = (_Float16)isg;
        bncoefh[128 + tid] = (_Float16)(btnext[tid] - mu * isg);
      }
    }
  }
}

// ---------------------------------------------------------------- fused pool+predict
__global__ __launch_bounds__(256) void k_poolpred(
    const float* __restrict__ h, const int* __restrict__ gstart,
    const float* __restrict__ statHs, const float* __restrict__ gamma,
    const float* __restrict__ beta, const float* __restrict__ pw,
    const float* __restrict__ pb, float* __restrict__ out) {
  __shared__ float sH[256];
  __shared__ float emb[128];
  __shared__ float4 red[256];
  int b = blockIdx.x, tid = threadIdx.x;
  {
    float a = 0.f;
#pragma unroll
    for (int s = 0; s < NSLOT; ++s) a += statHs[s * 256 + tid];
    sH[tid] = a;
  }
  int fl = (tid & 31) << 2, ns = tid >> 5;
  int gs = gstart[b], ge = gstart[b + 1];
  float4 acc = make_float4(0.f, 0.f, 0.f, 0.f);
  for (int n = gs + ns; n < ge; n += 8) {
    float4 v = *(const float4*)&h[(size_t)n * D + fl];
    acc.x += v.x; acc.y += v.y; acc.z += v.z; acc.w += v.w;
  }
  red[tid] = acc;
  __syncthreads();
  if (ns < 4) {
    float4 o = red[tid + 128];
    acc.x += o.x; acc.y += o.y; acc.z += o.z; acc.w += o.w;
    red[tid] = acc;
  }
  __syncthreads();
  if (ns < 2) {
    float4 o = red[tid + 64];
    acc.x += o.x; acc.y += o.y; acc.z += o.z; acc.w += o.w;
    red[tid] = acc;
  }
  __syncthreads();
  if (ns == 0) {
    float4 o = red[tid + 32];
    acc.x += o.x; acc.y += o.y; acc.z += o.z; acc.w += o.w;
    const float invN = 1.0f / (float)N_NODES;
    float inv = (ge > gs) ? 1.0f / (float)(ge - gs) : 0.f;
    float av[4] = {acc.x, acc.y, acc.z, acc.w};
#pragma unroll
    for (int j = 0; j < 4; ++j) {
      int k = fl + j;
      float mu = sH[k] * invN;
      float var = sH[D + k] * invN - mu * mu;
      emb[k] = (ge > gs)
          ? (av[j] * inv - mu) * rsqrtf(var + BN_EPS_F) * gamma[k] + beta[k]
          : 0.f;
    }
  }
  __syncthreads();
  if (tid < NTARGET) {
    float o = pb[tid];
    for (int k = 0; k < D; ++k) o += emb[k] * pw[k * NTARGET + tid];
    out[b * NTARGET + tid] = o;
  }
}

// ---------------------------------------------------------------- launch
extern "C" void kernel_launch(void* const* d_in, const int* in_sizes, int n_in,
                              void* d_out, int out_size, void* d_ws, size_t ws_size,
                              hipStream_t stream) {
  const int* x      = (const int*)d_in[0];
  const int* ei     = (const int*)d_in[1];
  const int* eattr  = (const int*)d_in[2];
  const int* batch  = (const int*)d_in[3];
  const int* aoff   = (const int*)d_in[4];
  const int* boff   = (const int*)d_in[5];
  const float* atab = (const float*)d_in[6];
  const float* btab = (const float*)d_in[7];
  const float* ngam = (const float*)d_in[8];
  const float* nbet = (const float*)d_in[9];
  const float* tptr = (const float*)d_in[10];
  const float* w1   = (const float*)d_in[11];
  const float* b1   = (const float*)d_in[12];
  const float* bng  = (const float*)d_in[13];
  const float* bnb  = (const float*)d_in[14];
  const float* w2   = (const float*)d_in[15];
  const float* b2   = (const float*)d_in[16];
  const float* pw   = (const float*)d_in[17];
  const float* pb   = (const float*)d_in[18];
  float* out = (float*)d_out;

  float* ws = (float*)d_ws;
  const size_t ND = (size_t)N_NODES * D;
  float* h      = ws;                          // ND fp32
  _Float16* hh  = (_Float16*)(ws + 1 * ND);    // ND halfs
  _Float16* xh  = (_Float16*)(ws + 1 * ND + ND / 2); // ND halfs
  _Float16* z1h = (_Float16*)(ws + 2 * ND);    // N*D2 halfs
  float* statAll = ws + 3 * ND;                // 7*NSLOT*(512+256) + 16
  float* stat1sAll = statAll;
  float* statHsAll = statAll + 7 * NSLOT * 512;
  int* done     = (int*)(statHsAll + 7 * NSLOT * 256);  // 16 ints (zeroed)
  _Float16* bncoefh = (_Float16*)(done + 16);  // 256 halfs
  float* comboF = (float*)(bncoefh + 256);
  _Float16* comboh = (_Float16*)comboF;        // 60*128 halfs
  _Float16* w1p = (_Float16*)(comboF + 60 * D / 2);
  _Float16* w2p = w1p + 7 * 32768;
  int* ibuf     = (int*)(w2p + 7 * 32768);
  int* rowptr   = ibuf;                        // N+1
  int* cursor   = rowptr + N_NODES + 1;        // N
  int* deg      = cursor + N_NODES;            // N
  int* payload  = deg + N_NODES;               // E
  int* gstart   = payload + N_EDGES;           // NGRAPH+1
  int* excl     = gstart + NGRAPH + 1;         // N
  int* bsum     = excl + N_NODES;              // 64
  int* hist     = bsum + 64;                   // 64
  int* cursor2  = hist + 64;                   // 64
  int* perm     = cursor2 + 64;                // N

  const int nodeBlocks = (N_NODES * 32 + 255) / 256;
  const int aggrBlocks = (N_NODES * 16 + 255) / 256;  // 3125
  const int edgeThreadBlocks = (N_EDGES + 255) / 256;
  const int gRows32 = (N_NODES + 31) / 32;     // 1563

  (void)hipMemsetAsync(statAll, 0,
                       ((size_t)7 * NSLOT * 768 + 16) * sizeof(float), stream);
  k_encode<<<nodeBlocks, 256, 0, stream>>>(x, aoff, atab, h, hh, deg);
  k_setup<<<451, 256, 0, stream>>>(w1, w2, w1p, w2p, boff, btab, comboh,
                                   batch, gstart, hist, bncoefh);
  k_degree<<<edgeThreadBlocks, 256, 0, stream>>>(ei, deg);
  k_scan1<<<NSB, 1024, 0, stream>>>(deg, excl, bsum, hist);
  k_scan2<<<1, 64, 0, stream>>>(bsum, hist, cursor2);
  k_scan3<<<(N_NODES + 256) / 256, 256, 0, stream>>>(excl, bsum, deg, cursor2,
                                                     rowptr, cursor, perm);
  k_scatter<<<edgeThreadBlocks, 256, 0, stream>>>(ei, eattr, cursor, payload);

  for (int l = 0; l < 7; ++l) {
    k_aggrx<<<aggrBlocks, 256, 0, stream>>>(
        hh, rowptr, payload, comboh, perm, tptr, l, bncoefh,
        l == 0 ? -65504.f : 0.f, xh);
    k_gemm1<<<gRows32, 256, 0, stream>>>(xh, w1p + (size_t)l * 32768,
                                         b1 + l * D2, z1h,
                                         stat1sAll + (size_t)l * NSLOT * 512);
    int nl = (l < 6) ? (l + 1) : 0;
    k_gemm2<<<gRows32, 256, 0, stream>>>(
        z1h, stat1sAll + (size_t)l * NSLOT * 512, bng + l * D2, bnb + l * D2,
        w2p + (size_t)l * 32768, b2 + l * D, h, hh, l > 0 ? 1 : 0,
        statHsAll + (size_t)l * NSLOT * 256,
        ngam + nl * D, nbet + nl * D, bncoefh, l < 6 ? 1 : 0, done);
  }

  k_poolpred<<<NGRAPH, 256, 0, stream>>>(h, gstart,
                                         statHsAll + (size_t)6 * NSLOT * 256,
                                         ngam, nbet, pw, pb, out);
}

// Round 15
// 824.308 us; speedup vs baseline: 2.2724x; 2.2724x over previous
//
#include <hip/hip_runtime.h>
#include <hip/hip_bf16.h>

#define N_NODES 50000
#define N_EDGES 600000
#define D 128
#define D2 256
#define NGRAPH 512
#define NTARGET 10
#define NSB 49   // scan blocks
#define NSLOT 32 // stat accumulation slots

static constexpr float MSG_EPS_F = 1e-7f;
static constexpr float BN_EPS_F  = 1e-5f;

typedef _Float16 half8 __attribute__((ext_vector_type(8)));
typedef _Float16 half4v __attribute__((ext_vector_type(4)));
typedef float f32x4 __attribute__((ext_vector_type(4)));
#define MFMA16(a, b, c) __builtin_amdgcn_mfma_f32_16x16x32_f16(a, b, c, 0, 0, 0)

// ---------------------------------------------------------------- encoder: h fp32 + hh fp16 (+ zero deg)
__global__ __launch_bounds__(256) void k_encode(
    const int* __restrict__ x, const int* __restrict__ aoff,
    const float* __restrict__ atab, float* __restrict__ h,
    _Float16* __restrict__ hh, int* __restrict__ deg) {
  int tid = blockIdx.x * 256 + threadIdx.x;
  if (tid < N_NODES) deg[tid] = 0;
  int n = tid >> 5, f4 = (tid & 31) << 2;
  if (n >= N_NODES) return;
  float4 acc = make_float4(0.f, 0.f, 0.f, 0.f);
#pragma unroll
  for (int i = 0; i < 9; ++i) {
    int row = x[n * 9 + i] + aoff[i];
    float4 v = *(const float4*)&atab[row * D + f4];
    acc.x += v.x; acc.y += v.y; acc.z += v.z; acc.w += v.w;
  }
  *(float4*)&h[(size_t)n * D + f4] = acc;
  half4v o = {(_Float16)acc.x, (_Float16)acc.y, (_Float16)acc.z, (_Float16)acc.w};
  *(half4v*)&hh[(size_t)n * D + f4] = o;
}

// ---------------------------------------------------------------- merged setup: packW + combo + gbounds + misc init
__global__ __launch_bounds__(256) void k_setup(
    const float* __restrict__ w1, const float* __restrict__ w2,
    _Float16* __restrict__ w1p, _Float16* __restrict__ w2p,
    const int* __restrict__ boff, const float* __restrict__ btab,
    _Float16* __restrict__ comboh, const int* __restrict__ batch,
    int* __restrict__ gstart, int* __restrict__ hist,
    _Float16* __restrict__ bncoefh) {
  int b = blockIdx.x, tid = threadIdx.x;
  if (b < 224) {            // weight pre-pack: 57344 threads
    int t = b * 256 + tid;
    if (t < 7 * 4096) {
      int lane = t & 63, ntAll = (t >> 6) & 15, kc = (t >> 10) & 3, l = t >> 12;
      int q = lane >> 4, c = ntAll * 16 + (lane & 15);
      int kbase = kc * 32 + q * 8;
      const float* W = w1 + (size_t)l * D * D2;
      half8 v;
#pragma unroll
      for (int j = 0; j < 8; ++j) v[j] = (_Float16)W[(size_t)(kbase + j) * D2 + c];
      *(half8*)&w1p[(size_t)t * 8] = v;
    } else {
      int u = t - 7 * 4096;
      int lane = u & 63, nt = (u >> 6) & 7, kcAll = (u >> 9) & 7, l = u >> 12;
      int q = lane >> 4, c = nt * 16 + (lane & 15);
      int kbase = kcAll * 32 + q * 8;
      const float* W = w2 + (size_t)l * D2 * D;
      half8 v;
#pragma unroll
      for (int j = 0; j < 8; ++j) v[j] = (_Float16)W[(size_t)(kbase + j) * D + c];
      *(half8*)&w2p[(size_t)u * 8] = v;
    }
  } else if (b < 254) {     // combo table: 60*128 threads
    int t = (b - 224) * 256 + tid;
    int c = t >> 7, f = t & 127;
    if (c < 60) {
      int a0 = c / 12, a1 = (c % 12) / 2, a2 = c % 2;
      comboh[c * D + f] = (_Float16)(btab[(boff[0] + a0) * D + f] +
                                     btab[(boff[1] + a1) * D + f] +
                                     btab[(boff[2] + a2) * D + f]);
    }
  } else if (b < 450) {     // graph bounds
    int n = (b - 254) * 256 + tid;
    if (n >= N_NODES) return;
    int b0 = batch[n];
    int b1 = (n + 1 < N_NODES) ? batch[n + 1] : NGRAPH;
    for (int bb = b0 + 1; bb <= b1; ++bb) gstart[bb] = n + 1;
    if (n == 0)
      for (int bb = 0; bb <= b0; ++bb) gstart[bb] = 0;
  } else {                  // misc: identity bncoef (layer 0), zero hist
    if (tid < 128) {
      bncoefh[tid] = (_Float16)1.f;
      bncoefh[128 + tid] = (_Float16)0.f;
    }
    if (tid < 64) hist[tid] = 0;
  }
}

// ---------------------------------------------------------------- CSR build
__global__ __launch_bounds__(256) void k_degree(
    const int* __restrict__ ei, int* __restrict__ deg) {
  int e = blockIdx.x * 256 + threadIdx.x;
  if (e >= N_EDGES) return;
  atomicAdd(&deg[ei[N_EDGES + e]], 1);
}

__global__ __launch_bounds__(1024) void k_scan1(
    const int* __restrict__ deg, int* __restrict__ excl,
    int* __restrict__ bsum, int* __restrict__ hist) {
  __shared__ int tmp[1024];
  __shared__ int lh[64];
  int t = threadIdx.x, i = blockIdx.x * 1024 + t;
  if (t < 64) lh[t] = 0;
  int v = (i < N_NODES) ? deg[i] : 0;
  tmp[t] = v;
  __syncthreads();
  if (i < N_NODES) atomicAdd(&lh[min(v, 63)], 1);
  for (int off = 1; off < 1024; off <<= 1) {
    int add = (t >= off) ? tmp[t - off] : 0;
    __syncthreads();
    tmp[t] += add;
    __syncthreads();
  }
  if (i < N_NODES) excl[i] = tmp[t] - v;
  if (t == 1023) bsum[blockIdx.x] = tmp[1023];
  __syncthreads();
  if (t < 64 && lh[t]) atomicAdd(&hist[t], lh[t]);
}

// merged: scan of block sums + scan of degree histogram
__global__ __launch_bounds__(64) void k_scan2(
    int* __restrict__ bsum, const int* __restrict__ hist,
    int* __restrict__ cursor2) {
  __shared__ int s[64], s2[64];
  int t = threadIdx.x;
  int v1 = (t < NSB) ? bsum[t] : 0;
  int v2 = hist[t];
  s[t] = v1; s2[t] = v2;
  __syncthreads();
  for (int off = 1; off < 64; off <<= 1) {
    int a1 = (t >= off) ? s[t - off] : 0;
    int a2 = (t >= off) ? s2[t - off] : 0;
    __syncthreads();
    s[t] += a1; s2[t] += a2;
    __syncthreads();
  }
  if (t < NSB) bsum[t] = s[t] - v1;
  cursor2[t] = s2[t] - v2;
}

// merged: rowptr/cursor finalize + degree-sorted permutation scatter
__global__ __launch_bounds__(256) void k_scan3(
    const int* __restrict__ excl, const int* __restrict__ bsum,
    const int* __restrict__ deg, int* __restrict__ cursor2,
    int* __restrict__ rowptr, int* __restrict__ cursor,
    int* __restrict__ perm) {
  __shared__ int lh[64], lbase[64];
  int tid = threadIdx.x;
  if (tid < 64) lh[tid] = 0;
  __syncthreads();
  int i = blockIdx.x * 256 + tid;
  int b = -1, lpos = 0;
  if (i < N_NODES) {
    int v = excl[i] + bsum[i >> 10];
    rowptr[i] = v;
    cursor[i] = v;
    b = min(deg[i], 63);
    lpos = atomicAdd(&lh[b], 1);
  }
  if (i == N_NODES) rowptr[N_NODES] = N_EDGES;
  __syncthreads();
  if (tid < 64 && lh[tid]) lbase[tid] = atomicAdd(&cursor2[tid], lh[tid]);
  __syncthreads();
  if (b >= 0) perm[lbase[b] + lpos] = i;
}

__global__ __launch_bounds__(256) void k_scatter(
    const int* __restrict__ ei, const int* __restrict__ eattr,
    int* __restrict__ cursor, int* __restrict__ payload) {
  int e = blockIdx.x * 256 + threadIdx.x;
  if (e >= N_EDGES) return;
  int src = ei[e], dst = ei[N_EDGES + e];
  int cid = eattr[e * 3 + 0] * 12 + eattr[e * 3 + 1] * 2 + eattr[e * 3 + 2];
  int pos = atomicAdd(&cursor[dst], 1);
  payload[pos] = (src << 6) | cid;
}

// ---------------------------------------------------------------- per-layer BN coefficients (1 block, fp16 out)
__global__ __launch_bounds__(128) void k_bncoef(
    const float* __restrict__ statHsPrev, const float* __restrict__ gamma,
    const float* __restrict__ beta, _Float16* __restrict__ bncoefh) {
  int t = threadIdx.x;
  float s = 0.f, sq = 0.f;
#pragma unroll
  for (int sl = 0; sl < NSLOT; ++sl) {
    s += statHsPrev[sl * 256 + t];
    sq += statHsPrev[sl * 256 + 128 + t];
  }
  const float invN = 1.0f / (float)N_NODES;
  float mu = s * invN, var = sq * invN - mu * mu;
  float isg = rsqrtf(var + BN_EPS_F) * gamma[t];
  bncoefh[t] = (_Float16)isg;
  bncoefh[128 + t] = (_Float16)(beta[t] - mu * isg);
}

// ---------------------------------------------------------------- aggregation (packed fp16 vectors, BN folded, eps folded, degree-sorted)
__global__ __launch_bounds__(256) void k_aggrx(
    const _Float16* __restrict__ hh, const int* __restrict__ rowptr,
    const int* __restrict__ payload, const _Float16* __restrict__ comboh,
    const int* __restrict__ perm, const float* __restrict__ tptr, int l,
    const _Float16* __restrict__ bncoefh, float negcap,
    _Float16* __restrict__ xh) {
  int tid = blockIdx.x * 256 + threadIdx.x;
  int gi = tid >> 4, f8 = (tid & 15) << 3;
  if (gi >= N_NODES) return;
  int dst = perm[gi];
  float tv = tptr[l];
  half8 a8 = *(const half8*)&bncoefh[f8];
  half8 b8 = *(const half8*)&bncoefh[128 + f8];
  half8 cap8, zero8;
#pragma unroll
  for (int j = 0; j < 8; ++j) { cap8[j] = (_Float16)negcap; zero8[j] = (_Float16)0.f; }
  int s = rowptr[dst], e = rowptr[dst + 1];
  float den[8], S[8];
#pragma unroll
  for (int j = 0; j < 8; ++j) { den[j] = 0.f; S[j] = 0.f; }
  int i = s;
  for (; i + 1 < e; i += 2) {
    int p0 = payload[i], p1 = payload[i + 1];
    half8 h0 = *(const half8*)&hh[(size_t)(p0 >> 6) * D + f8];
    half8 h1 = *(const half8*)&hh[(size_t)(p1 >> 6) * D + f8];
    half8 c0 = *(const half8*)&comboh[(p0 & 63) * D + f8];
    half8 c1 = *(const half8*)&comboh[(p1 & 63) * D + f8];
    half8 r0 = __builtin_elementwise_max(h0 * a8 + b8, cap8);
    half8 m0 = __builtin_elementwise_max(r0 + c0, zero8);
    half8 r1 = __builtin_elementwise_max(h1 * a8 + b8, cap8);
    half8 m1 = __builtin_elementwise_max(r1 + c1, zero8);
#pragma unroll
    for (int j = 0; j < 8; ++j) {
      float mf0 = (float)m0[j], mf1 = (float)m1[j];
      float e0 = __expf(mf0 * tv), e1 = __expf(mf1 * tv);
      den[j] += e0 + e1;
      S[j] += mf0 * e0 + mf1 * e1;
    }
  }
  if (i < e) {
    int p0 = payload[i];
    half8 h0 = *(const half8*)&hh[(size_t)(p0 >> 6) * D + f8];
    half8 c0 = *(const half8*)&comboh[(p0 & 63) * D + f8];
    half8 r0 = __builtin_elementwise_max(h0 * a8 + b8, cap8);
    half8 m0 = __builtin_elementwise_max(r0 + c0, zero8);
#pragma unroll
    for (int j = 0; j < 8; ++j) {
      float mf0 = (float)m0[j];
      float e0 = __expf(mf0 * tv);
      den[j] += e0;
      S[j] += mf0 * e0;
    }
  }
  half8 hd = *(const half8*)&hh[(size_t)dst * D + f8];
  half8 rd = __builtin_elementwise_max(hd * a8 + b8, cap8);
  half8 o;
#pragma unroll
  for (int j = 0; j < 8; ++j)
    o[j] = (_Float16)((float)rd[j] + S[j] / (den[j] + 1e-16f) + MSG_EPS_F);
  *(half8*)&xh[(size_t)dst * D + f8] = o;
}

// ---------------------------------------------------------------- GEMM1 (MFMA fp16): z1h = fp16(xh @ W1 + b1); slotted stats
__global__ __launch_bounds__(256) void k_gemm1(
    const _Float16* __restrict__ xh, const _Float16* __restrict__ w1p,
    const float* __restrict__ b1, _Float16* __restrict__ z1h,
    float* __restrict__ stat1s) {
  __shared__ __align__(16) _Float16 Af[512 * 8];   // 8 KB
  int tid = threadIdx.x;
  int row0 = blockIdx.x * 32;
  int slot = blockIdx.x & (NSLOT - 1);

#pragma unroll
  for (int s0 = 0; s0 < 2; ++s0) {
    int s = s0 * 256 + tid;
    int kc = s >> 7, mt = (s >> 6) & 1, l2 = s & 63;
    int row = row0 + mt * 16 + (l2 & 15);
    int kb = kc * 32 + ((l2 >> 4) << 3);
    half8 v;
    if (row < N_NODES) {
      v = *(const half8*)&xh[(size_t)row * D + kb];
    } else {
#pragma unroll
      for (int j = 0; j < 8; ++j) v[j] = (_Float16)0.f;
    }
    *(half8*)&Af[s * 8] = v;
  }
  __syncthreads();

  int wv = tid >> 6, ln = tid & 63;
  f32x4 acc[2][4];
#pragma unroll
  for (int i = 0; i < 2; ++i)
#pragma unroll
    for (int j = 0; j < 4; ++j) acc[i][j] = (f32x4){0.f, 0.f, 0.f, 0.f};

#pragma unroll
  for (int kc = 0; kc < 4; ++kc) {
    half8 a0 = *(half8*)&Af[((kc * 2 + 0) * 64 + ln) * 8];
    half8 a1 = *(half8*)&Af[((kc * 2 + 1) * 64 + ln) * 8];
#pragma unroll
    for (int nt = 0; nt < 4; ++nt) {
      int ntAll = wv * 4 + nt;
      half8 b = *(const half8*)&w1p[((size_t)(kc * 16 + ntAll) * 64 + ln) * 8];
      acc[0][nt] = MFMA16(a0, b, acc[0][nt]);
      acc[1][nt] = MFMA16(a1, b, acc[1][nt]);
    }
  }
  int lq = ln >> 4, lc = ln & 15;
  float cs[4], cq[4];
#pragma unroll
  for (int nt = 0; nt < 4; ++nt) { cs[nt] = 0.f; cq[nt] = 0.f; }
#pragma unroll
  for (int nt = 0; nt < 4; ++nt) {
    int col = (wv * 4 + nt) * 16 + lc;
    float bias = b1[col];
#pragma unroll
    for (int mt = 0; mt < 2; ++mt) {
      int rbase = row0 + mt * 16 + lq * 4;
#pragma unroll
      for (int rg = 0; rg < 4; ++rg) {
        int row = rbase + rg;
        if (row < N_NODES) {
          float z = acc[mt][nt][rg] + bias;
          z1h[(size_t)row * D2 + col] = (_Float16)z;
          cs[nt] += z; cq[nt] += z * z;
        }
      }
    }
  }
#pragma unroll
  for (int nt = 0; nt < 4; ++nt) {
    float v = cs[nt], q = cq[nt];
    v += __shfl_xor(v, 16); v += __shfl_xor(v, 32);
    q += __shfl_xor(q, 16); q += __shfl_xor(q, 32);
    if (lq == 0) {
      int col = (wv * 4 + nt) * 16 + lc;
      atomicAdd(&stat1s[slot * 512 + col], v);
      atomicAdd(&stat1s[slot * 512 + 256 + col], q);
    }
  }
}

// ---------------------------------------------------------------- GEMM2: h = relu(BN(z1)) @ W2 + b2 (+h); writes h fp32 + hh fp16
__global__ __launch_bounds__(256) void k_gemm2(
    const _Float16* __restrict__ z1h, const float* __restrict__ stat1s,
    const float* __restrict__ g1, const float* __restrict__ bt1,
    const _Float16* __restrict__ w2p, const float* __restrict__ b2,
    float* __restrict__ h, _Float16* __restrict__ hh, int residual,
    float* __restrict__ statHs) {
  __shared__ __align__(16) _Float16 Af[1024 * 8];   // 16 KB
  __shared__ float s1[512];
  const float invN = 1.0f / (float)N_NODES;
  int tid = threadIdx.x;
  int row0 = blockIdx.x * 32;
  int slot = blockIdx.x & (NSLOT - 1);

#pragma unroll
  for (int jj = 0; jj < 2; ++jj) {
    int j = jj * 256 + tid;
    float a = 0.f;
#pragma unroll
    for (int s = 0; s < NSLOT; ++s) a += stat1s[s * 512 + j];
    s1[j] = a;
  }
  __syncthreads();

#pragma unroll
  for (int s0 = 0; s0 < 4; ++s0) {
    int s = s0 * 256 + tid;
    int kcAll = s >> 7, mt = (s >> 6) & 1, l2 = s & 63;
    int row = row0 + mt * 16 + (l2 & 15);
    int kb = kcAll * 32 + ((l2 >> 4) << 3);
    half8 v;
    if (row < N_NODES) {
      half8 z = *(const half8*)&z1h[(size_t)row * D2 + kb];
#pragma unroll
      for (int j = 0; j < 8; ++j) {
        float mu = s1[kb + j] * invN;
        float isg = rsqrtf(s1[256 + kb + j] * invN - mu * mu + BN_EPS_F) * g1[kb + j];
        v[j] = (_Float16)fmaxf(((float)z[j] - mu) * isg + bt1[kb + j], 0.f);
      }
    } else {
#pragma unroll
      for (int j = 0; j < 8; ++j) v[j] = (_Float16)0.f;
    }
    *(half8*)&Af[s * 8] = v;
  }
  __syncthreads();

  int wv = tid >> 6, ln = tid & 63;
  f32x4 acc[2][2];
#pragma unroll
  for (int i = 0; i < 2; ++i)
#pragma unroll
    for (int j = 0; j < 2; ++j) acc[i][j] = (f32x4){0.f, 0.f, 0.f, 0.f};

#pragma unroll
  for (int kcAll = 0; kcAll < 8; ++kcAll) {
    half8 a0 = *(half8*)&Af[((kcAll * 2 + 0) * 64 + ln) * 8];
    half8 a1 = *(half8*)&Af[((kcAll * 2 + 1) * 64 + ln) * 8];
#pragma unroll
    for (int nt = 0; nt < 2; ++nt) {
      half8 b = *(const half8*)&w2p[((size_t)(kcAll * 8 + wv * 2 + nt) * 64 + ln) * 8];
      acc[0][nt] = MFMA16(a0, b, acc[0][nt]);
      acc[1][nt] = MFMA16(a1, b, acc[1][nt]);
    }
  }
  int lq = ln >> 4, lc = ln & 15;
  float cs[2], cq[2];
#pragma unroll
  for (int nt = 0; nt < 2; ++nt) { cs[nt] = 0.f; cq[nt] = 0.f; }
#pragma unroll
  for (int nt = 0; nt < 2; ++nt) {
    int col = (wv * 2 + nt) * 16 + lc;
    float bias = b2[col];
#pragma unroll
    for (int mt = 0; mt < 2; ++mt) {
      int rbase = row0 + mt * 16 + lq * 4;
#pragma unroll
      for (int rg = 0; rg < 4; ++rg) {
        int row = rbase + rg;
        if (row < N_NODES) {
          float v = acc[mt][nt][rg] + bias;
          if (residual) v += h[(size_t)row * D + col];
          h[(size_t)row * D + col] = v;
          hh[(size_t)row * D + col] = (_Float16)v;
          cs[nt] += v; cq[nt] += v * v;
        }
      }
    }
  }
#pragma unroll
  for (int nt = 0; nt < 2; ++nt) {
    float v = cs[nt], q = cq[nt];
    v += __shfl_xor(v, 16); v += __shfl_xor(v, 32);
    q += __shfl_xor(q, 16); q += __shfl_xor(q, 32);
    if (lq == 0) {
      int col = (wv * 2 + nt) * 16 + lc;
      atomicAdd(&statHs[slot * 256 + col], v);
      atomicAdd(&statHs[slot * 256 + 128 + col], q);
    }
  }
}

// ---------------------------------------------------------------- fused pool+predict
__global__ __launch_bounds__(256) void k_poolpred(
    const float* __restrict__ h, const int* __restrict__ gstart,
    const float* __restrict__ statHs, const float* __restrict__ gamma,
    const float* __restrict__ beta, const float* __restrict__ pw,
    const float* __restrict__ pb, float* __restrict__ out) {
  __shared__ float sH[256];
  __shared__ float emb[128];
  __shared__ float4 red[256];
  int b = blockIdx.x, tid = threadIdx.x;
  {
    float a = 0.f;
#pragma unroll
    for (int s = 0; s < NSLOT; ++s) a += statHs[s * 256 + tid];
    sH[tid] = a;
  }
  int fl = (tid & 31) << 2, ns = tid >> 5;
  int gs = gstart[b], ge = gstart[b + 1];
  float4 acc = make_float4(0.f, 0.f, 0.f, 0.f);
  for (int n = gs + ns; n < ge; n += 8) {
    float4 v = *(const float4*)&h[(size_t)n * D + fl];
    acc.x += v.x; acc.y += v.y; acc.z += v.z; acc.w += v.w;
  }
  red[tid] = acc;
  __syncthreads();
  if (ns < 4) {
    float4 o = red[tid + 128];
    acc.x += o.x; acc.y += o.y; acc.z += o.z; acc.w += o.w;
    red[tid] = acc;
  }
  __syncthreads();
  if (ns < 2) {
    float4 o = red[tid + 64];
    acc.x += o.x; acc.y += o.y; acc.z += o.z; acc.w += o.w;
    red[tid] = acc;
  }
  __syncthreads();
  if (ns == 0) {
    float4 o = red[tid + 32];
    acc.x += o.x; acc.y += o.y; acc.z += o.z; acc.w += o.w;
    const float invN = 1.0f / (float)N_NODES;
    float inv = (ge > gs) ? 1.0f / (float)(ge - gs) : 0.f;
    float av[4] = {acc.x, acc.y, acc.z, acc.w};
#pragma unroll
    for (int j = 0; j < 4; ++j) {
      int k = fl + j;
      float mu = sH[k] * invN;
      float var = sH[D + k] * invN - mu * mu;
      emb[k] = (ge > gs)
          ? (av[j] * inv - mu) * rsqrtf(var + BN_EPS_F) * gamma[k] + beta[k]
          : 0.f;
    }
  }
  __syncthreads();
  if (tid < NTARGET) {
    float o = pb[tid];
    for (int k = 0; k < D; ++k) o += emb[k] * pw[k * NTARGET + tid];
    out[b * NTARGET + tid] = o;
  }
}

// ---------------------------------------------------------------- launch
extern "C" void kernel_launch(void* const* d_in, const int* in_sizes, int n_in,
                              void* d_out, int out_size, void* d_ws, size_t ws_size,
                              hipStream_t stream) {
  const int* x      = (const int*)d_in[0];
  const int* ei     = (const int*)d_in[1];
  const int* eattr  = (const int*)d_in[2];
  const int* batch  = (const int*)d_in[3];
  const int* aoff   = (const int*)d_in[4];
  const int* boff   = (const int*)d_in[5];
  const float* atab = (const float*)d_in[6];
  const float* btab = (const float*)d_in[7];
  const float* ngam = (const float*)d_in[8];
  const float* nbet = (const float*)d_in[9];
  const float* tptr = (const float*)d_in[10];
  const float* w1   = (const float*)d_in[11];
  const float* b1   = (const float*)d_in[12];
  const float* bng  = (const float*)d_in[13];
  const float* bnb  = (const float*)d_in[14];
  const float* w2   = (const float*)d_in[15];
  const float* b2   = (const float*)d_in[16];
  const float* pw   = (const float*)d_in[17];
  const float* pb   = (const float*)d_in[18];
  float* out = (float*)d_out;

  float* ws = (float*)d_ws;
  const size_t ND = (size_t)N_NODES * D;
  float* h      = ws;                          // ND fp32
  _Float16* hh  = (_Float16*)(ws + 1 * ND);    // ND halfs
  _Float16* xh  = (_Float16*)(ws + 1 * ND + ND / 2); // ND halfs
  _Float16* z1h = (_Float16*)(ws + 2 * ND);    // N*D2 halfs
  float* statAll = ws + 3 * ND;                // 7*NSLOT*(512+256)
  float* stat1sAll = statAll;
  float* statHsAll = statAll + 7 * NSLOT * 512;
  _Float16* bncoefh = (_Float16*)(statHsAll + 7 * NSLOT * 256);  // 256 halfs
  float* comboF = (float*)(bncoefh + 256);
  _Float16* comboh = (_Float16*)comboF;        // 60*128 halfs
  _Float16* w1p = (_Float16*)(comboF + 60 * D / 2);
  _Float16* w2p = w1p + 7 * 32768;
  int* ibuf     = (int*)(w2p + 7 * 32768);
  int* rowptr   = ibuf;                        // N+1
  int* cursor   = rowptr + N_NODES + 1;        // N
  int* deg      = cursor + N_NODES;            // N
  int* payload  = deg + N_NODES;               // E
  int* gstart   = payload + N_EDGES;           // NGRAPH+1
  int* excl     = gstart + NGRAPH + 1;         // N
  int* bsum     = excl + N_NODES;              // 64
  int* hist     = bsum + 64;                   // 64
  int* cursor2  = hist + 64;                   // 64
  int* perm     = cursor2 + 64;                // N

  const int nodeBlocks = (N_NODES * 32 + 255) / 256;
  const int aggrBlocks = (N_NODES * 16 + 255) / 256;  // 3125
  const int edgeThreadBlocks = (N_EDGES + 255) / 256;
  const int gRows32 = (N_NODES + 31) / 32;     // 1563

  (void)hipMemsetAsync(statAll, 0,
                       (size_t)7 * NSLOT * 768 * sizeof(float), stream);
  k_encode<<<nodeBlocks, 256, 0, stream>>>(x, aoff, atab, h, hh, deg);
  k_setup<<<451, 256, 0, stream>>>(w1, w2, w1p, w2p, boff, btab, comboh,
                                   batch, gstart, hist, bncoefh);
  k_degree<<<edgeThreadBlocks, 256, 0, stream>>>(ei, deg);
  k_scan1<<<NSB, 1024, 0, stream>>>(deg, excl, bsum, hist);
  k_scan2<<<1, 64, 0, stream>>>(bsum, hist, cursor2);
  k_scan3<<<(N_NODES + 256) / 256, 256, 0, stream>>>(excl, bsum, deg, cursor2,
                                                     rowptr, cursor, perm);
  k_scatter<<<edgeThreadBlocks, 256, 0, stream>>>(ei, eattr, cursor, payload);

  for (int l = 0; l < 7; ++l) {
    if (l > 0)
      k_bncoef<<<1, 128, 0, stream>>>(statHsAll + (size_t)(l - 1) * NSLOT * 256,
                                      ngam + l * D, nbet + l * D, bncoefh);
    k_aggrx<<<aggrBlocks, 256, 0, stream>>>(
        hh, rowptr, payload, comboh, perm, tptr, l, bncoefh,
        l == 0 ? -65504.f : 0.f, xh);
    k_gemm1<<<gRows32, 256, 0, stream>>>(xh, w1p + (size_t)l * 32768,
                                         b1 + l * D2, z1h,
                                         stat1sAll + (size_t)l * NSLOT * 512);
    k_gemm2<<<gRows32, 256, 0, stream>>>(
        z1h, stat1sAll + (size_t)l * NSLOT * 512, bng + l * D2, bnb + l * D2,
        w2p + (size_t)l * 32768, b2 + l * D, h, hh, l > 0 ? 1 : 0,
        statHsAll + (size_t)l * NSLOT * 256);
  }

  k_poolpred<<<NGRAPH, 256, 0, stream>>>(h, gstart,
                                         statHsAll + (size_t)6 * NSLOT * 256,
                                         ngam, nbet, pw, pb, out);
}

// Round 16
// 811.519 us; speedup vs baseline: 2.3082x; 1.0158x over previous
//
#include <hip/hip_runtime.h>
#include <hip/hip_bf16.h>

#define N_NODES 50000
#define N_EDGES 600000
#define D 128
#define D2 256
#define NGRAPH 512
#define NTARGET 10
#define NSB 49   // scan blocks
#define NSLOT 32 // stat accumulation slots

static constexpr float MSG_EPS_F = 1e-7f;
static constexpr float BN_EPS_F  = 1e-5f;

typedef _Float16 half8 __attribute__((ext_vector_type(8)));
typedef _Float16 half4v __attribute__((ext_vector_type(4)));
typedef float f32x4 __attribute__((ext_vector_type(4)));
#define MFMA16(a, b, c) __builtin_amdgcn_mfma_f32_16x16x32_f16(a, b, c, 0, 0, 0)

// ---------------------------------------------------------------- encoder: h fp32 + hh fp16 (+ zero deg)
__global__ __launch_bounds__(256) void k_encode(
    const int* __restrict__ x, const int* __restrict__ aoff,
    const float* __restrict__ atab, float* __restrict__ h,
    _Float16* __restrict__ hh, int* __restrict__ deg) {
  int tid = blockIdx.x * 256 + threadIdx.x;
  if (tid < N_NODES) deg[tid] = 0;
  int n = tid >> 5, f4 = (tid & 31) << 2;
  if (n >= N_NODES) return;
  float4 acc = make_float4(0.f, 0.f, 0.f, 0.f);
#pragma unroll
  for (int i = 0; i < 9; ++i) {
    int row = x[n * 9 + i] + aoff[i];
    float4 v = *(const float4*)&atab[row * D + f4];
    acc.x += v.x; acc.y += v.y; acc.z += v.z; acc.w += v.w;
  }
  *(float4*)&h[(size_t)n * D + f4] = acc;
  half4v o = {(_Float16)acc.x, (_Float16)acc.y, (_Float16)acc.z, (_Float16)acc.w};
  *(half4v*)&hh[(size_t)n * D + f4] = o;
}

// ---------------------------------------------------------------- merged setup: packW + combo + gbounds + misc init
__global__ __launch_bounds__(256) void k_setup(
    const float* __restrict__ w1, const float* __restrict__ w2,
    _Float16* __restrict__ w1p, _Float16* __restrict__ w2p,
    const int* __restrict__ boff, const float* __restrict__ btab,
    _Float16* __restrict__ comboh, const int* __restrict__ batch,
    int* __restrict__ gstart, int* __restrict__ hist,
    _Float16* __restrict__ bncoefh) {
  int b = blockIdx.x, tid = threadIdx.x;
  if (b < 224) {            // weight pre-pack: 57344 threads
    int t = b * 256 + tid;
    if (t < 7 * 4096) {
      int lane = t & 63, ntAll = (t >> 6) & 15, kc = (t >> 10) & 3, l = t >> 12;
      int q = lane >> 4, c = ntAll * 16 + (lane & 15);
      int kbase = kc * 32 + q * 8;
      const float* W = w1 + (size_t)l * D * D2;
      half8 v;
#pragma unroll
      for (int j = 0; j < 8; ++j) v[j] = (_Float16)W[(size_t)(kbase + j) * D2 + c];
      *(half8*)&w1p[(size_t)t * 8] = v;
    } else {
      int u = t - 7 * 4096;
      int lane = u & 63, nt = (u >> 6) & 7, kcAll = (u >> 9) & 7, l = u >> 12;
      int q = lane >> 4, c = nt * 16 + (lane & 15);
      int kbase = kcAll * 32 + q * 8;
      const float* W = w2 + (size_t)l * D2 * D;
      half8 v;
#pragma unroll
      for (int j = 0; j < 8; ++j) v[j] = (_Float16)W[(size_t)(kbase + j) * D + c];
      *(half8*)&w2p[(size_t)u * 8] = v;
    }
  } else if (b < 254) {     // combo table: 60*128 threads
    int t = (b - 224) * 256 + tid;
    int c = t >> 7, f = t & 127;
    if (c < 60) {
      int a0 = c / 12, a1 = (c % 12) / 2, a2 = c % 2;
      comboh[c * D + f] = (_Float16)(btab[(boff[0] + a0) * D + f] +
                                     btab[(boff[1] + a1) * D + f] +
                                     btab[(boff[2] + a2) * D + f]);
    }
  } else if (b < 450) {     // graph bounds
    int n = (b - 254) * 256 + tid;
    if (n >= N_NODES) return;
    int b0 = batch[n];
    int b1 = (n + 1 < N_NODES) ? batch[n + 1] : NGRAPH;
    for (int bb = b0 + 1; bb <= b1; ++bb) gstart[bb] = n + 1;
    if (n == 0)
      for (int bb = 0; bb <= b0; ++bb) gstart[bb] = 0;
  } else {                  // misc: identity bncoef (layer 0), zero hist
    if (tid < 128) {
      bncoefh[tid] = (_Float16)1.f;
      bncoefh[128 + tid] = (_Float16)0.f;
    }
    if (tid < 64) hist[tid] = 0;
  }
}

// ---------------------------------------------------------------- CSR build
__global__ __launch_bounds__(256) void k_degree(
    const int* __restrict__ ei, int* __restrict__ deg) {
  int e = blockIdx.x * 256 + threadIdx.x;
  if (e >= N_EDGES) return;
  atomicAdd(&deg[ei[N_EDGES + e]], 1);
}

__global__ __launch_bounds__(1024) void k_scan1(
    const int* __restrict__ deg, int* __restrict__ excl,
    int* __restrict__ bsum, int* __restrict__ hist) {
  __shared__ int tmp[1024];
  __shared__ int lh[64];
  int t = threadIdx.x, i = blockIdx.x * 1024 + t;
  if (t < 64) lh[t] = 0;
  int v = (i < N_NODES) ? deg[i] : 0;
  tmp[t] = v;
  __syncthreads();
  if (i < N_NODES) atomicAdd(&lh[min(v, 63)], 1);
  for (int off = 1; off < 1024; off <<= 1) {
    int add = (t >= off) ? tmp[t - off] : 0;
    __syncthreads();
    tmp[t] += add;
    __syncthreads();
  }
  if (i < N_NODES) excl[i] = tmp[t] - v;
  if (t == 1023) bsum[blockIdx.x] = tmp[1023];
  __syncthreads();
  if (t < 64 && lh[t]) atomicAdd(&hist[t], lh[t]);
}

// merged: scan of block sums + scan of degree histogram
__global__ __launch_bounds__(64) void k_scan2(
    int* __restrict__ bsum, const int* __restrict__ hist,
    int* __restrict__ cursor2) {
  __shared__ int s[64], s2[64];
  int t = threadIdx.x;
  int v1 = (t < NSB) ? bsum[t] : 0;
  int v2 = hist[t];
  s[t] = v1; s2[t] = v2;
  __syncthreads();
  for (int off = 1; off < 64; off <<= 1) {
    int a1 = (t >= off) ? s[t - off] : 0;
    int a2 = (t >= off) ? s2[t - off] : 0;
    __syncthreads();
    s[t] += a1; s2[t] += a2;
    __syncthreads();
  }
  if (t < NSB) bsum[t] = s[t] - v1;
  cursor2[t] = s2[t] - v2;
}

// merged: rowptr/cursor finalize + degree-sorted permutation scatter
__global__ __launch_bounds__(256) void k_scan3(
    const int* __restrict__ excl, const int* __restrict__ bsum,
    const int* __restrict__ deg, int* __restrict__ cursor2,
    int* __restrict__ rowptr, int* __restrict__ cursor,
    int* __restrict__ perm) {
  __shared__ int lh[64], lbase[64];
  int tid = threadIdx.x;
  if (tid < 64) lh[tid] = 0;
  __syncthreads();
  int i = blockIdx.x * 256 + tid;
  int b = -1, lpos = 0;
  if (i < N_NODES) {
    int v = excl[i] + bsum[i >> 10];
    rowptr[i] = v;
    cursor[i] = v;
    b = min(deg[i], 63);
    lpos = atomicAdd(&lh[b], 1);
  }
  if (i == N_NODES) rowptr[N_NODES] = N_EDGES;
  __syncthreads();
  if (tid < 64 && lh[tid]) lbase[tid] = atomicAdd(&cursor2[tid], lh[tid]);
  __syncthreads();
  if (b >= 0) perm[lbase[b] + lpos] = i;
}

__global__ __launch_bounds__(256) void k_scatter(
    const int* __restrict__ ei, const int* __restrict__ eattr,
    int* __restrict__ cursor, int* __restrict__ payload) {
  int e = blockIdx.x * 256 + threadIdx.x;
  if (e >= N_EDGES) return;
  int src = ei[e], dst = ei[N_EDGES + e];
  int cid = eattr[e * 3 + 0] * 12 + eattr[e * 3 + 1] * 2 + eattr[e * 3 + 2];
  int pos = atomicAdd(&cursor[dst], 1);
  payload[pos] = (src << 6) | cid;
}

// ---------------------------------------------------------------- per-layer BN coefficients (1 block, fp16 out)
__global__ __launch_bounds__(128) void k_bncoef(
    const float* __restrict__ statHsPrev, const float* __restrict__ gamma,
    const float* __restrict__ beta, _Float16* __restrict__ bncoefh) {
  int t = threadIdx.x;
  float s = 0.f, sq = 0.f;
#pragma unroll
  for (int sl = 0; sl < NSLOT; ++sl) {
    s += statHsPrev[sl * 256 + t];
    sq += statHsPrev[sl * 256 + 128 + t];
  }
  const float invN = 1.0f / (float)N_NODES;
  float mu = s * invN, var = sq * invN - mu * mu;
  float isg = rsqrtf(var + BN_EPS_F) * gamma[t];
  bncoefh[t] = (_Float16)isg;
  bncoefh[128 + t] = (_Float16)(beta[t] - mu * isg);
}

// ---------------------------------------------------------------- aggregation (packed fp16, BN/eps folded, degree-sorted, 4x unroll)
__global__ __launch_bounds__(256) void k_aggrx(
    const _Float16* __restrict__ hh, const int* __restrict__ rowptr,
    const int* __restrict__ payload, const _Float16* __restrict__ comboh,
    const int* __restrict__ perm, const float* __restrict__ tptr, int l,
    const _Float16* __restrict__ bncoefh, float negcap,
    _Float16* __restrict__ xh) {
  int tid = blockIdx.x * 256 + threadIdx.x;
  int gi = tid >> 4, f8 = (tid & 15) << 3;
  if (gi >= N_NODES) return;
  int dst = perm[gi];
  float tv = tptr[l];
  half8 a8 = *(const half8*)&bncoefh[f8];
  half8 b8 = *(const half8*)&bncoefh[128 + f8];
  half8 cap8, zero8;
#pragma unroll
  for (int j = 0; j < 8; ++j) { cap8[j] = (_Float16)negcap; zero8[j] = (_Float16)0.f; }
  int s = rowptr[dst], e = rowptr[dst + 1];
  float den[8], S[8];
#pragma unroll
  for (int j = 0; j < 8; ++j) { den[j] = 0.f; S[j] = 0.f; }
  int i = s;
  for (; i + 3 < e; i += 4) {
    int p0 = payload[i], p1 = payload[i + 1];
    int p2 = payload[i + 2], p3 = payload[i + 3];
    half8 h0 = *(const half8*)&hh[(size_t)(p0 >> 6) * D + f8];
    half8 h1 = *(const half8*)&hh[(size_t)(p1 >> 6) * D + f8];
    half8 h2 = *(const half8*)&hh[(size_t)(p2 >> 6) * D + f8];
    half8 h3 = *(const half8*)&hh[(size_t)(p3 >> 6) * D + f8];
    half8 c0 = *(const half8*)&comboh[(p0 & 63) * D + f8];
    half8 c1 = *(const half8*)&comboh[(p1 & 63) * D + f8];
    half8 c2 = *(const half8*)&comboh[(p2 & 63) * D + f8];
    half8 c3 = *(const half8*)&comboh[(p3 & 63) * D + f8];
    half8 m0 = __builtin_elementwise_max(
        __builtin_elementwise_max(h0 * a8 + b8, cap8) + c0, zero8);
    half8 m1 = __builtin_elementwise_max(
        __builtin_elementwise_max(h1 * a8 + b8, cap8) + c1, zero8);
    half8 m2 = __builtin_elementwise_max(
        __builtin_elementwise_max(h2 * a8 + b8, cap8) + c2, zero8);
    half8 m3 = __builtin_elementwise_max(
        __builtin_elementwise_max(h3 * a8 + b8, cap8) + c3, zero8);
#pragma unroll
    for (int j = 0; j < 8; ++j) {
      float mf0 = (float)m0[j], mf1 = (float)m1[j];
      float mf2 = (float)m2[j], mf3 = (float)m3[j];
      float e0 = __expf(mf0 * tv), e1 = __expf(mf1 * tv);
      float e2 = __expf(mf2 * tv), e3 = __expf(mf3 * tv);
      den[j] += (e0 + e1) + (e2 + e3);
      S[j] += (mf0 * e0 + mf1 * e1) + (mf2 * e2 + mf3 * e3);
    }
  }
  for (; i < e; ++i) {
    int p0 = payload[i];
    half8 h0 = *(const half8*)&hh[(size_t)(p0 >> 6) * D + f8];
    half8 c0 = *(const half8*)&comboh[(p0 & 63) * D + f8];
    half8 m0 = __builtin_elementwise_max(
        __builtin_elementwise_max(h0 * a8 + b8, cap8) + c0, zero8);
#pragma unroll
    for (int j = 0; j < 8; ++j) {
      float mf0 = (float)m0[j];
      float e0 = __expf(mf0 * tv);
      den[j] += e0;
      S[j] += mf0 * e0;
    }
  }
  half8 hd = *(const half8*)&hh[(size_t)dst * D + f8];
  half8 rd = __builtin_elementwise_max(hd * a8 + b8, cap8);
  half8 o;
#pragma unroll
  for (int j = 0; j < 8; ++j)
    o[j] = (_Float16)((float)rd[j] + S[j] / (den[j] + 1e-16f) + MSG_EPS_F);
  *(half8*)&xh[(size_t)dst * D + f8] = o;
}

// ---------------------------------------------------------------- GEMM1 (MFMA fp16): z1h = fp16(xh @ W1 + b1); slotted stats
__global__ __launch_bounds__(256) void k_gemm1(
    const _Float16* __restrict__ xh, const _Float16* __restrict__ w1p,
    const float* __restrict__ b1, _Float16* __restrict__ z1h,
    float* __restrict__ stat1s) {
  __shared__ __align__(16) _Float16 Af[512 * 8];   // 8 KB
  int tid = threadIdx.x;
  int row0 = blockIdx.x * 32;
  int slot = blockIdx.x & (NSLOT - 1);

#pragma unroll
  for (int s0 = 0; s0 < 2; ++s0) {
    int s = s0 * 256 + tid;
    int kc = s >> 7, mt = (s >> 6) & 1, l2 = s & 63;
    int row = row0 + mt * 16 + (l2 & 15);
    int kb = kc * 32 + ((l2 >> 4) << 3);
    half8 v;
    if (row < N_NODES) {
      v = *(const half8*)&xh[(size_t)row * D + kb];
    } else {
#pragma unroll
      for (int j = 0; j < 8; ++j) v[j] = (_Float16)0.f;
    }
    *(half8*)&Af[s * 8] = v;
  }
  __syncthreads();

  int wv = tid >> 6, ln = tid & 63;
  f32x4 acc[2][4];
#pragma unroll
  for (int i = 0; i < 2; ++i)
#pragma unroll
    for (int j = 0; j < 4; ++j) acc[i][j] = (f32x4){0.f, 0.f, 0.f, 0.f};

#pragma unroll
  for (int kc = 0; kc < 4; ++kc) {
    half8 a0 = *(half8*)&Af[((kc * 2 + 0) * 64 + ln) * 8];
    half8 a1 = *(half8*)&Af[((kc * 2 + 1) * 64 + ln) * 8];
#pragma unroll
    for (int nt = 0; nt < 4; ++nt) {
      int ntAll = wv * 4 + nt;
      half8 b = *(const half8*)&w1p[((size_t)(kc * 16 + ntAll) * 64 + ln) * 8];
      acc[0][nt] = MFMA16(a0, b, acc[0][nt]);
      acc[1][nt] = MFMA16(a1, b, acc[1][nt]);
    }
  }
  int lq = ln >> 4, lc = ln & 15;
  float cs[4], cq[4];
#pragma unroll
  for (int nt = 0; nt < 4; ++nt) { cs[nt] = 0.f; cq[nt] = 0.f; }
#pragma unroll
  for (int nt = 0; nt < 4; ++nt) {
    int col = (wv * 4 + nt) * 16 + lc;
    float bias = b1[col];
#pragma unroll
    for (int mt = 0; mt < 2; ++mt) {
      int rbase = row0 + mt * 16 + lq * 4;
#pragma unroll
      for (int rg = 0; rg < 4; ++rg) {
        int row = rbase + rg;
        if (row < N_NODES) {
          float z = acc[mt][nt][rg] + bias;
          z1h[(size_t)row * D2 + col] = (_Float16)z;
          cs[nt] += z; cq[nt] += z * z;
        }
      }
    }
  }
#pragma unroll
  for (int nt = 0; nt < 4; ++nt) {
    float v = cs[nt], q = cq[nt];
    v += __shfl_xor(v, 16); v += __shfl_xor(v, 32);
    q += __shfl_xor(q, 16); q += __shfl_xor(q, 32);
    if (lq == 0) {
      int col = (wv * 4 + nt) * 16 + lc;
      atomicAdd(&stat1s[slot * 512 + col], v);
      atomicAdd(&stat1s[slot * 512 + 256 + col], q);
    }
  }
}

// ---------------------------------------------------------------- GEMM2: h = relu(BN(z1)) @ W2 + b2 (+h); writes h fp32 + hh fp16
__global__ __launch_bounds__(256) void k_gemm2(
    const _Float16* __restrict__ z1h, const float* __restrict__ stat1s,
    const float* __restrict__ g1, const float* __restrict__ bt1,
    const _Float16* __restrict__ w2p, const float* __restrict__ b2,
    float* __restrict__ h, _Float16* __restrict__ hh, int residual,
    float* __restrict__ statHs) {
  __shared__ __align__(16) _Float16 Af[1024 * 8];   // 16 KB
  __shared__ float s1[512];
  const float invN = 1.0f / (float)N_NODES;
  int tid = threadIdx.x;
  int row0 = blockIdx.x * 32;
  int slot = blockIdx.x & (NSLOT - 1);

#pragma unroll
  for (int jj = 0; jj < 2; ++jj) {
    int j = jj * 256 + tid;
    float a = 0.f;
#pragma unroll
    for (int s = 0; s < NSLOT; ++s) a += stat1s[s * 512 + j];
    s1[j] = a;
  }
  __syncthreads();

#pragma unroll
  for (int s0 = 0; s0 < 4; ++s0) {
    int s = s0 * 256 + tid;
    int kcAll = s >> 7, mt = (s >> 6) & 1, l2 = s & 63;
    int row = row0 + mt * 16 + (l2 & 15);
    int kb = kcAll * 32 + ((l2 >> 4) << 3);
    half8 v;
    if (row < N_NODES) {
      half8 z = *(const half8*)&z1h[(size_t)row * D2 + kb];
#pragma unroll
      for (int j = 0; j < 8; ++j) {
        float mu = s1[kb + j] * invN;
        float isg = rsqrtf(s1[256 + kb + j] * invN - mu * mu + BN_EPS_F) * g1[kb + j];
        v[j] = (_Float16)fmaxf(((float)z[j] - mu) * isg + bt1[kb + j], 0.f);
      }
    } else {
#pragma unroll
      for (int j = 0; j < 8; ++j) v[j] = (_Float16)0.f;
    }
    *(half8*)&Af[s * 8] = v;
  }
  __syncthreads();

  int wv = tid >> 6, ln = tid & 63;
  f32x4 acc[2][2];
#pragma unroll
  for (int i = 0; i < 2; ++i)
#pragma unroll
    for (int j = 0; j < 2; ++j) acc[i][j] = (f32x4){0.f, 0.f, 0.f, 0.f};

#pragma unroll
  for (int kcAll = 0; kcAll < 8; ++kcAll) {
    half8 a0 = *(half8*)&Af[((kcAll * 2 + 0) * 64 + ln) * 8];
    half8 a1 = *(half8*)&Af[((kcAll * 2 + 1) * 64 + ln) * 8];
#pragma unroll
    for (int nt = 0; nt < 2; ++nt) {
      half8 b = *(const half8*)&w2p[((size_t)(kcAll * 8 + wv * 2 + nt) * 64 + ln) * 8];
      acc[0][nt] = MFMA16(a0, b, acc[0][nt]);
      acc[1][nt] = MFMA16(a1, b, acc[1][nt]);
    }
  }
  int lq = ln >> 4, lc = ln & 15;
  float cs[2], cq[2];
#pragma unroll
  for (int nt = 0; nt < 2; ++nt) { cs[nt] = 0.f; cq[nt] = 0.f; }
#pragma unroll
  for (int nt = 0; nt < 2; ++nt) {
    int col = (wv * 2 + nt) * 16 + lc;
    float bias = b2[col];
#pragma unroll
    for (int mt = 0; mt < 2; ++mt) {
      int rbase = row0 + mt * 16 + lq * 4;
#pragma unroll
      for (int rg = 0; rg < 4; ++rg) {
        int row = rbase + rg;
        if (row < N_NODES) {
          float v = acc[mt][nt][rg] + bias;
          if (residual) v += h[(size_t)row * D + col];
          h[(size_t)row * D + col] = v;
          hh[(size_t)row * D + col] = (_Float16)v;
          cs[nt] += v; cq[nt] += v * v;
        }
      }
    }
  }
#pragma unroll
  for (int nt = 0; nt < 2; ++nt) {
    float v = cs[nt], q = cq[nt];
    v += __shfl_xor(v, 16); v += __shfl_xor(v, 32);
    q += __shfl_xor(q, 16); q += __shfl_xor(q, 32);
    if (lq == 0) {
      int col = (wv * 2 + nt) * 16 + lc;
      atomicAdd(&statHs[slot * 256 + col], v);
      atomicAdd(&statHs[slot * 256 + 128 + col], q);
    }
  }
}

// ---------------------------------------------------------------- fused pool+predict
__global__ __launch_bounds__(256) void k_poolpred(
    const float* __restrict__ h, const int* __restrict__ gstart,
    const float* __restrict__ statHs, const float* __restrict__ gamma,
    const float* __restrict__ beta, const float* __restrict__ pw,
    const float* __restrict__ pb, float* __restrict__ out) {
  __shared__ float sH[256];
  __shared__ float emb[128];
  __shared__ float4 red[256];
  int b = blockIdx.x, tid = threadIdx.x;
  {
    float a = 0.f;
#pragma unroll
    for (int s = 0; s < NSLOT; ++s) a += statHs[s * 256 + tid];
    sH[tid] = a;
  }
  int fl = (tid & 31) << 2, ns = tid >> 5;
  int gs = gstart[b], ge = gstart[b + 1];
  float4 acc = make_float4(0.f, 0.f, 0.f, 0.f);
  for (int n = gs + ns; n < ge; n += 8) {
    float4 v = *(const float4*)&h[(size_t)n * D + fl];
    acc.x += v.x; acc.y += v.y; acc.z += v.z; acc.w += v.w;
  }
  red[tid] = acc;
  __syncthreads();
  if (ns < 4) {
    float4 o = red[tid + 128];
    acc.x += o.x; acc.y += o.y; acc.z += o.z; acc.w += o.w;
    red[tid] = acc;
  }
  __syncthreads();
  if (ns < 2) {
    float4 o = red[tid + 64];
    acc.x += o.x; acc.y += o.y; acc.z += o.z; acc.w += o.w;
    red[tid] = acc;
  }
  __syncthreads();
  if (ns == 0) {
    float4 o = red[tid + 32];
    acc.x += o.x; acc.y += o.y; acc.z += o.z; acc.w += o.w;
    const float invN = 1.0f / (float)N_NODES;
    float inv = (ge > gs) ? 1.0f / (float)(ge - gs) : 0.f;
    float av[4] = {acc.x, acc.y, acc.z, acc.w};
#pragma unroll
    for (int j = 0; j < 4; ++j) {
      int k = fl + j;
      float mu = sH[k] * invN;
      float var = sH[D + k] * invN - mu * mu;
      emb[k] = (ge > gs)
          ? (av[j] * inv - mu) * rsqrtf(var + BN_EPS_F) * gamma[k] + beta[k]
          : 0.f;
    }
  }
  __syncthreads();
  if (tid < NTARGET) {
    float o = pb[tid];
    for (int k = 0; k < D; ++k) o += emb[k] * pw[k * NTARGET + tid];
    out[b * NTARGET + tid] = o;
  }
}

// ---------------------------------------------------------------- launch
extern "C" void kernel_launch(void* const* d_in, const int* in_sizes, int n_in,
                              void* d_out, int out_size, void* d_ws, size_t ws_size,
                              hipStream_t stream) {
  const int* x      = (const int*)d_in[0];
  const int* ei     = (const int*)d_in[1];
  const int* eattr  = (const int*)d_in[2];
  const int* batch  = (const int*)d_in[3];
  const int* aoff   = (const int*)d_in[4];
  const int* boff   = (const int*)d_in[5];
  const float* atab = (const float*)d_in[6];
  const float* btab = (const float*)d_in[7];
  const float* ngam = (const float*)d_in[8];
  const float* nbet = (const float*)d_in[9];
  const float* tptr = (const float*)d_in[10];
  const float* w1   = (const float*)d_in[11];
  const float* b1   = (const float*)d_in[12];
  const float* bng  = (const float*)d_in[13];
  const float* bnb  = (const float*)d_in[14];
  const float* w2   = (const float*)d_in[15];
  const float* b2   = (const float*)d_in[16];
  const float* pw   = (const float*)d_in[17];
  const float* pb   = (const float*)d_in[18];
  float* out = (float*)d_out;

  float* ws = (float*)d_ws;
  const size_t ND = (size_t)N_NODES * D;
  float* h      = ws;                          // ND fp32
  _Float16* hh  = (_Float16*)(ws + 1 * ND);    // ND halfs
  _Float16* xh  = (_Float16*)(ws + 1 * ND + ND / 2); // ND halfs
  _Float16* z1h = (_Float16*)(ws + 2 * ND);    // N*D2 halfs
  float* statAll = ws + 3 * ND;                // 7*NSLOT*(512+256)
  float* stat1sAll = statAll;
  float* statHsAll = statAll + 7 * NSLOT * 512;
  _Float16* bncoefh = (_Float16*)(statHsAll + 7 * NSLOT * 256);  // 256 halfs
  float* comboF = (float*)(bncoefh + 256);
  _Float16* comboh = (_Float16*)comboF;        // 60*128 halfs
  _Float16* w1p = (_Float16*)(comboF + 60 * D / 2);
  _Float16* w2p = w1p + 7 * 32768;
  int* ibuf     = (int*)(w2p + 7 * 32768);
  int* rowptr   = ibuf;                        // N+1
  int* cursor   = rowptr + N_NODES + 1;        // N
  int* deg      = cursor + N_NODES;            // N
  int* payload  = deg + N_NODES;               // E
  int* gstart   = payload + N_EDGES;           // NGRAPH+1
  int* excl     = gstart + NGRAPH + 1;         // N
  int* bsum     = excl + N_NODES;              // 64
  int* hist     = bsum + 64;                   // 64
  int* cursor2  = hist + 64;                   // 64
  int* perm     = cursor2 + 64;                // N

  const int nodeBlocks = (N_NODES * 32 + 255) / 256;
  const int aggrBlocks = (N_NODES * 16 + 255) / 256;  // 3125
  const int edgeThreadBlocks = (N_EDGES + 255) / 256;
  const int gRows32 = (N_NODES + 31) / 32;     // 1563

  (void)hipMemsetAsync(statAll, 0,
                       (size_t)7 * NSLOT * 768 * sizeof(float), stream);
  k_encode<<<nodeBlocks, 256, 0, stream>>>(x, aoff, atab, h, hh, deg);
  k_setup<<<451, 256, 0, stream>>>(w1, w2, w1p, w2p, boff, btab, comboh,
                                   batch, gstart, hist, bncoefh);
  k_degree<<<edgeThreadBlocks, 256, 0, stream>>>(ei, deg);
  k_scan1<<<NSB, 1024, 0, stream>>>(deg, excl, bsum, hist);
  k_scan2<<<1, 64, 0, stream>>>(bsum, hist, cursor2);
  k_scan3<<<(N_NODES + 256) / 256, 256, 0, stream>>>(excl, bsum, deg, cursor2,
                                                     rowptr, cursor, perm);
  k_scatter<<<edgeThreadBlocks, 256, 0, stream>>>(ei, eattr, cursor, payload);

  for (int l = 0; l < 7; ++l) {
    if (l > 0)
      k_bncoef<<<1, 128, 0, stream>>>(statHsAll + (size_t)(l - 1) * NSLOT * 256,
                                      ngam + l * D, nbet + l * D, bncoefh);
    k_aggrx<<<aggrBlocks, 256, 0, stream>>>(
        hh, rowptr, payload, comboh, perm, tptr, l, bncoefh,
        l == 0 ? -65504.f : 0.f, xh);
    k_gemm1<<<gRows32, 256, 0, stream>>>(xh, w1p + (size_t)l * 32768,
                                         b1 + l * D2, z1h,
                                         stat1sAll + (size_t)l * NSLOT * 512);
    k_gemm2<<<gRows32, 256, 0, stream>>>(
        z1h, stat1sAll + (size_t)l * NSLOT * 512, bng + l * D2, bnb + l * D2,
        w2p + (size_t)l * 32768, b2 + l * D, h, hh, l > 0 ? 1 : 0,
        statHsAll + (size_t)l * NSLOT * 256);
  }

  k_poolpred<<<NGRAPH, 256, 0, stream>>>(h, gstart,
                                         statHsAll + (size_t)6 * NSLOT * 256,
                                         ngam, nbet, pw, pb, out);
}

// Round 17
// 798.374 us; speedup vs baseline: 2.3463x; 1.0165x over previous
//
#include <hip/hip_runtime.h>
#include <hip/hip_bf16.h>

#define N_NODES 50000
#define N_EDGES 600000
#define D 128
#define D2 256
#define NGRAPH 512
#define NTARGET 10
#define NSB 49   // scan blocks
#define NSLOT 32 // stat accumulation slots

static constexpr float MSG_EPS_F = 1e-7f;
static constexpr float BN_EPS_F  = 1e-5f;

typedef _Float16 half8 __attribute__((ext_vector_type(8)));
typedef _Float16 half4v __attribute__((ext_vector_type(4)));
typedef float f32x4 __attribute__((ext_vector_type(4)));
#define MFMA16(a, b, c) __builtin_amdgcn_mfma_f32_16x16x32_f16(a, b, c, 0, 0, 0)

// ---------------------------------------------------------------- encoder: h fp32 + hh fp16 (+ zero deg)
__global__ __launch_bounds__(256) void k_encode(
    const int* __restrict__ x, const int* __restrict__ aoff,
    const float* __restrict__ atab, float* __restrict__ h,
    _Float16* __restrict__ hh, int* __restrict__ deg) {
  int tid = blockIdx.x * 256 + threadIdx.x;
  if (tid < N_NODES) deg[tid] = 0;
  int n = tid >> 5, f4 = (tid & 31) << 2;
  if (n >= N_NODES) return;
  float4 acc = make_float4(0.f, 0.f, 0.f, 0.f);
#pragma unroll
  for (int i = 0; i < 9; ++i) {
    int row = x[n * 9 + i] + aoff[i];
    float4 v = *(const float4*)&atab[row * D + f4];
    acc.x += v.x; acc.y += v.y; acc.z += v.z; acc.w += v.w;
  }
  *(float4*)&h[(size_t)n * D + f4] = acc;
  half4v o = {(_Float16)acc.x, (_Float16)acc.y, (_Float16)acc.z, (_Float16)acc.w};
  *(half4v*)&hh[(size_t)n * D + f4] = o;
}

// ---------------------------------------------------------------- merged setup: packW + combo + gbounds + misc init
__global__ __launch_bounds__(256) void k_setup(
    const float* __restrict__ w1, const float* __restrict__ w2,
    _Float16* __restrict__ w1p, _Float16* __restrict__ w2p,
    const int* __restrict__ boff, const float* __restrict__ btab,
    _Float16* __restrict__ comboh, const int* __restrict__ batch,
    int* __restrict__ gstart, int* __restrict__ hist,
    _Float16* __restrict__ bncoefh) {
  int b = blockIdx.x, tid = threadIdx.x;
  if (b < 224) {            // weight pre-pack: 57344 threads
    int t = b * 256 + tid;
    if (t < 7 * 4096) {
      int lane = t & 63, ntAll = (t >> 6) & 15, kc = (t >> 10) & 3, l = t >> 12;
      int q = lane >> 4, c = ntAll * 16 + (lane & 15);
      int kbase = kc * 32 + q * 8;
      const float* W = w1 + (size_t)l * D * D2;
      half8 v;
#pragma unroll
      for (int j = 0; j < 8; ++j) v[j] = (_Float16)W[(size_t)(kbase + j) * D2 + c];
      *(half8*)&w1p[(size_t)t * 8] = v;
    } else {
      int u = t - 7 * 4096;
      int lane = u & 63, nt = (u >> 6) & 7, kcAll = (u >> 9) & 7, l = u >> 12;
      int q = lane >> 4, c = nt * 16 + (lane & 15);
      int kbase = kcAll * 32 + q * 8;
      const float* W = w2 + (size_t)l * D2 * D;
      half8 v;
#pragma unroll
      for (int j = 0; j < 8; ++j) v[j] = (_Float16)W[(size_t)(kbase + j) * D + c];
      *(half8*)&w2p[(size_t)u * 8] = v;
    }
  } else if (b < 254) {     // combo table: 60*128 threads
    int t = (b - 224) * 256 + tid;
    int c = t >> 7, f = t & 127;
    if (c < 60) {
      int a0 = c / 12, a1 = (c % 12) / 2, a2 = c % 2;
      comboh[c * D + f] = (_Float16)(btab[(boff[0] + a0) * D + f] +
                                     btab[(boff[1] + a1) * D + f] +
                                     btab[(boff[2] + a2) * D + f]);
    }
  } else if (b < 450) {     // graph bounds
    int n = (b - 254) * 256 + tid;
    if (n >= N_NODES) return;
    int b0 = batch[n];
    int b1 = (n + 1 < N_NODES) ? batch[n + 1] : NGRAPH;
    for (int bb = b0 + 1; bb <= b1; ++bb) gstart[bb] = n + 1;
    if (n == 0)
      for (int bb = 0; bb <= b0; ++bb) gstart[bb] = 0;
  } else {                  // misc: identity bncoef (layer 0), zero hist
    if (tid < 128) {
      bncoefh[tid] = (_Float16)1.f;
      bncoefh[128 + tid] = (_Float16)0.f;
    }
    if (tid < 64) hist[tid] = 0;
  }
}

// ---------------------------------------------------------------- CSR build
__global__ __launch_bounds__(256) void k_degree(
    const int* __restrict__ ei, int* __restrict__ deg) {
  int e = blockIdx.x * 256 + threadIdx.x;
  if (e >= N_EDGES) return;
  atomicAdd(&deg[ei[N_EDGES + e]], 1);
}

__global__ __launch_bounds__(1024) void k_scan1(
    const int* __restrict__ deg, int* __restrict__ excl,
    int* __restrict__ bsum, int* __restrict__ hist) {
  __shared__ int tmp[1024];
  __shared__ int lh[64];
  int t = threadIdx.x, i = blockIdx.x * 1024 + t;
  if (t < 64) lh[t] = 0;
  int v = (i < N_NODES) ? deg[i] : 0;
  tmp[t] = v;
  __syncthreads();
  if (i < N_NODES) atomicAdd(&lh[min(v, 63)], 1);
  for (int off = 1; off < 1024; off <<= 1) {
    int add = (t >= off) ? tmp[t - off] : 0;
    __syncthreads();
    tmp[t] += add;
    __syncthreads();
  }
  if (i < N_NODES) excl[i] = tmp[t] - v;
  if (t == 1023) bsum[blockIdx.x] = tmp[1023];
  __syncthreads();
  if (t < 64 && lh[t]) atomicAdd(&hist[t], lh[t]);
}

// merged: scan of block sums + scan of degree histogram
__global__ __launch_bounds__(64) void k_scan2(
    int* __restrict__ bsum, const int* __restrict__ hist,
    int* __restrict__ cursor2) {
  __shared__ int s[64], s2[64];
  int t = threadIdx.x;
  int v1 = (t < NSB) ? bsum[t] : 0;
  int v2 = hist[t];
  s[t] = v1; s2[t] = v2;
  __syncthreads();
  for (int off = 1; off < 64; off <<= 1) {
    int a1 = (t >= off) ? s[t - off] : 0;
    int a2 = (t >= off) ? s2[t - off] : 0;
    __syncthreads();
    s[t] += a1; s2[t] += a2;
    __syncthreads();
  }
  if (t < NSB) bsum[t] = s[t] - v1;
  cursor2[t] = s2[t] - v2;
}

// merged: rowptr/cursor finalize + degree-sorted permutation scatter
__global__ __launch_bounds__(256) void k_scan3(
    const int* __restrict__ excl, const int* __restrict__ bsum,
    const int* __restrict__ deg, int* __restrict__ cursor2,
    int* __restrict__ rowptr, int* __restrict__ cursor,
    int* __restrict__ perm) {
  __shared__ int lh[64], lbase[64];
  int tid = threadIdx.x;
  if (tid < 64) lh[tid] = 0;
  __syncthreads();
  int i = blockIdx.x * 256 + tid;
  int b = -1, lpos = 0;
  if (i < N_NODES) {
    int v = excl[i] + bsum[i >> 10];
    rowptr[i] = v;
    cursor[i] = v;
    b = min(deg[i], 63);
    lpos = atomicAdd(&lh[b], 1);
  }
  if (i == N_NODES) rowptr[N_NODES] = N_EDGES;
  __syncthreads();
  if (tid < 64 && lh[tid]) lbase[tid] = atomicAdd(&cursor2[tid], lh[tid]);
  __syncthreads();
  if (b >= 0) perm[lbase[b] + lpos] = i;
}

__global__ __launch_bounds__(256) void k_scatter(
    const int* __restrict__ ei, const int* __restrict__ eattr,
    int* __restrict__ cursor, int* __restrict__ payload) {
  int e = blockIdx.x * 256 + threadIdx.x;
  if (e >= N_EDGES) return;
  int src = ei[e], dst = ei[N_EDGES + e];
  int cid = eattr[e * 3 + 0] * 12 + eattr[e * 3 + 1] * 2 + eattr[e * 3 + 2];
  int pos = atomicAdd(&cursor[dst], 1);
  payload[pos] = (src << 6) | cid;
}

// ---------------------------------------------------------------- per-layer BN coefficients (1 block, fp16 out)
__global__ __launch_bounds__(128) void k_bncoef(
    const float* __restrict__ statHsPrev, const float* __restrict__ gamma,
    const float* __restrict__ beta, _Float16* __restrict__ bncoefh) {
  int t = threadIdx.x;
  float s = 0.f, sq = 0.f;
#pragma unroll
  for (int sl = 0; sl < NSLOT; ++sl) {
    s += statHsPrev[sl * 256 + t];
    sq += statHsPrev[sl * 256 + 128 + t];
  }
  const float invN = 1.0f / (float)N_NODES;
  float mu = s * invN, var = sq * invN - mu * mu;
  float isg = rsqrtf(var + BN_EPS_F) * gamma[t];
  bncoefh[t] = (_Float16)isg;
  bncoefh[128 + t] = (_Float16)(beta[t] - mu * isg);
}

// ---------------------------------------------------------------- aggregation (packed fp16, BN/eps folded, degree-sorted, 4x unroll)
__global__ __launch_bounds__(256) void k_aggrx(
    const _Float16* __restrict__ hh, const int* __restrict__ rowptr,
    const int* __restrict__ payload, const _Float16* __restrict__ comboh,
    const int* __restrict__ perm, const float* __restrict__ tptr, int l,
    const _Float16* __restrict__ bncoefh, float negcap,
    _Float16* __restrict__ xh) {
  int tid = blockIdx.x * 256 + threadIdx.x;
  int gi = tid >> 4, f8 = (tid & 15) << 3;
  if (gi >= N_NODES) return;
  int dst = perm[gi];
  float tv = tptr[l];
  half8 a8 = *(const half8*)&bncoefh[f8];
  half8 b8 = *(const half8*)&bncoefh[128 + f8];
  half8 cap8, zero8;
#pragma unroll
  for (int j = 0; j < 8; ++j) { cap8[j] = (_Float16)negcap; zero8[j] = (_Float16)0.f; }
  int s = rowptr[dst], e = rowptr[dst + 1];
  float den[8], S[8];
#pragma unroll
  for (int j = 0; j < 8; ++j) { den[j] = 0.f; S[j] = 0.f; }
  int i = s;
  for (; i + 3 < e; i += 4) {
    int p0 = payload[i], p1 = payload[i + 1];
    int p2 = payload[i + 2], p3 = payload[i + 3];
    half8 h0 = *(const half8*)&hh[(size_t)(p0 >> 6) * D + f8];
    half8 h1 = *(const half8*)&hh[(size_t)(p1 >> 6) * D + f8];
    half8 h2 = *(const half8*)&hh[(size_t)(p2 >> 6) * D + f8];
    half8 h3 = *(const half8*)&hh[(size_t)(p3 >> 6) * D + f8];
    half8 c0 = *(const half8*)&comboh[(p0 & 63) * D + f8];
    half8 c1 = *(const half8*)&comboh[(p1 & 63) * D + f8];
    half8 c2 = *(const half8*)&comboh[(p2 & 63) * D + f8];
    half8 c3 = *(const half8*)&comboh[(p3 & 63) * D + f8];
    half8 m0 = __builtin_elementwise_max(
        __builtin_elementwise_max(h0 * a8 + b8, cap8) + c0, zero8);
    half8 m1 = __builtin_elementwise_max(
        __builtin_elementwise_max(h1 * a8 + b8, cap8) + c1, zero8);
    half8 m2 = __builtin_elementwise_max(
        __builtin_elementwise_max(h2 * a8 + b8, cap8) + c2, zero8);
    half8 m3 = __builtin_elementwise_max(
        __builtin_elementwise_max(h3 * a8 + b8, cap8) + c3, zero8);
#pragma unroll
    for (int j = 0; j < 8; ++j) {
      float mf0 = (float)m0[j], mf1 = (float)m1[j];
      float mf2 = (float)m2[j], mf3 = (float)m3[j];
      float e0 = __expf(mf0 * tv), e1 = __expf(mf1 * tv);
      float e2 = __expf(mf2 * tv), e3 = __expf(mf3 * tv);
      den[j] += (e0 + e1) + (e2 + e3);
      S[j] += (mf0 * e0 + mf1 * e1) + (mf2 * e2 + mf3 * e3);
    }
  }
  for (; i < e; ++i) {
    int p0 = payload[i];
    half8 h0 = *(const half8*)&hh[(size_t)(p0 >> 6) * D + f8];
    half8 c0 = *(const half8*)&comboh[(p0 & 63) * D + f8];
    half8 m0 = __builtin_elementwise_max(
        __builtin_elementwise_max(h0 * a8 + b8, cap8) + c0, zero8);
#pragma unroll
    for (int j = 0; j < 8; ++j) {
      float mf0 = (float)m0[j];
      float e0 = __expf(mf0 * tv);
      den[j] += e0;
      S[j] += mf0 * e0;
    }
  }
  half8 hd = *(const half8*)&hh[(size_t)dst * D + f8];
  half8 rd = __builtin_elementwise_max(hd * a8 + b8, cap8);
  half8 o;
#pragma unroll
  for (int j = 0; j < 8; ++j)
    o[j] = (_Float16)((float)rd[j] + S[j] / (den[j] + 1e-16f) + MSG_EPS_F);
  *(half8*)&xh[(size_t)dst * D + f8] = o;
}

// ---------------------------------------------------------------- GEMM1 (MFMA fp16): z1h = fp16(xh @ W1 + b1); slotted stats
__global__ __launch_bounds__(256) void k_gemm1(
    const _Float16* __restrict__ xh, const _Float16* __restrict__ w1p,
    const float* __restrict__ b1, _Float16* __restrict__ z1h,
    float* __restrict__ stat1s) {
  __shared__ __align__(16) _Float16 Af[512 * 8];   // 8 KB
  int tid = threadIdx.x;
  int row0 = blockIdx.x * 32;
  int slot = blockIdx.x & (NSLOT - 1);

#pragma unroll
  for (int s0 = 0; s0 < 2; ++s0) {
    int s = s0 * 256 + tid;
    int kc = s >> 7, mt = (s >> 6) & 1, l2 = s & 63;
    int row = row0 + mt * 16 + (l2 & 15);
    int kb = kc * 32 + ((l2 >> 4) << 3);
    half8 v;
    if (row < N_NODES) {
      v = *(const half8*)&xh[(size_t)row * D + kb];
    } else {
#pragma unroll
      for (int j = 0; j < 8; ++j) v[j] = (_Float16)0.f;
    }
    *(half8*)&Af[s * 8] = v;
  }
  __syncthreads();

  int wv = tid >> 6, ln = tid & 63;
  f32x4 acc[2][4];
#pragma unroll
  for (int i = 0; i < 2; ++i)
#pragma unroll
    for (int j = 0; j < 4; ++j) acc[i][j] = (f32x4){0.f, 0.f, 0.f, 0.f};

#pragma unroll
  for (int kc = 0; kc < 4; ++kc) {
    half8 a0 = *(half8*)&Af[((kc * 2 + 0) * 64 + ln) * 8];
    half8 a1 = *(half8*)&Af[((kc * 2 + 1) * 64 + ln) * 8];
#pragma unroll
    for (int nt = 0; nt < 4; ++nt) {
      int ntAll = wv * 4 + nt;
      half8 b = *(const half8*)&w1p[((size_t)(kc * 16 + ntAll) * 64 + ln) * 8];
      acc[0][nt] = MFMA16(a0, b, acc[0][nt]);
      acc[1][nt] = MFMA16(a1, b, acc[1][nt]);
    }
  }
  int lq = ln >> 4, lc = ln & 15;
  float cs[4], cq[4];
#pragma unroll
  for (int nt = 0; nt < 4; ++nt) { cs[nt] = 0.f; cq[nt] = 0.f; }
#pragma unroll
  for (int nt = 0; nt < 4; ++nt) {
    int col = (wv * 4 + nt) * 16 + lc;
    float bias = b1[col];
#pragma unroll
    for (int mt = 0; mt < 2; ++mt) {
      int rbase = row0 + mt * 16 + lq * 4;
#pragma unroll
      for (int rg = 0; rg < 4; ++rg) {
        int row = rbase + rg;
        if (row < N_NODES) {
          float z = acc[mt][nt][rg] + bias;
          z1h[(size_t)row * D2 + col] = (_Float16)z;
          cs[nt] += z; cq[nt] += z * z;
        }
      }
    }
  }
#pragma unroll
  for (int nt = 0; nt < 4; ++nt) {
    float v = cs[nt], q = cq[nt];
    v += __shfl_xor(v, 16); v += __shfl_xor(v, 32);
    q += __shfl_xor(q, 16); q += __shfl_xor(q, 32);
    if (lq == 0) {
      int col = (wv * 4 + nt) * 16 + lc;
      atomicAdd(&stat1s[slot * 512 + col], v);
      atomicAdd(&stat1s[slot * 512 + 256 + col], q);
    }
  }
}

// ---------------------------------------------------------------- GEMM2: h = relu(BN(z1)) @ W2 + b2 (+h); z1h register-prefetched
__global__ __launch_bounds__(256) void k_gemm2(
    const _Float16* __restrict__ z1h, const float* __restrict__ stat1s,
    const float* __restrict__ g1, const float* __restrict__ bt1,
    const _Float16* __restrict__ w2p, const float* __restrict__ b2,
    float* __restrict__ h, _Float16* __restrict__ hh, int residual,
    int writeHH, float* __restrict__ statHs) {
  __shared__ __align__(16) _Float16 Af[1024 * 8];   // 16 KB
  __shared__ float s1[512];
  const float invN = 1.0f / (float)N_NODES;
  int tid = threadIdx.x;
  int row0 = blockIdx.x * 32;
  int slot = blockIdx.x & (NSLOT - 1);

  // --- prefetch z1h fragments into registers BEFORE the stat reduce ---
  half8 zpre[4];
  int prow[4], pkb[4];
#pragma unroll
  for (int s0 = 0; s0 < 4; ++s0) {
    int s = s0 * 256 + tid;
    int kcAll = s >> 7, mt = (s >> 6) & 1, l2 = s & 63;
    int row = row0 + mt * 16 + (l2 & 15);
    int kb = kcAll * 32 + ((l2 >> 4) << 3);
    prow[s0] = row; pkb[s0] = kb;
    if (row < N_NODES) {
      zpre[s0] = *(const half8*)&z1h[(size_t)row * D2 + kb];
    } else {
#pragma unroll
      for (int j = 0; j < 8; ++j) zpre[s0][j] = (_Float16)0.f;
    }
  }

  // --- stat1 slot-reduce (overlaps with the z1h loads above) ---
#pragma unroll
  for (int jj = 0; jj < 2; ++jj) {
    int j = jj * 256 + tid;
    float a = 0.f;
#pragma unroll
    for (int s = 0; s < NSLOT; ++s) a += stat1s[s * 512 + j];
    s1[j] = a;
  }
  __syncthreads();

#pragma unroll
  for (int s0 = 0; s0 < 4; ++s0) {
    int s = s0 * 256 + tid;
    int kb = pkb[s0];
    half8 v;
    if (prow[s0] < N_NODES) {
      half8 z = zpre[s0];
#pragma unroll
      for (int j = 0; j < 8; ++j) {
        float mu = s1[kb + j] * invN;
        float isg = rsqrtf(s1[256 + kb + j] * invN - mu * mu + BN_EPS_F) * g1[kb + j];
        v[j] = (_Float16)fmaxf(((float)z[j] - mu) * isg + bt1[kb + j], 0.f);
      }
    } else {
#pragma unroll
      for (int j = 0; j < 8; ++j) v[j] = (_Float16)0.f;
    }
    *(half8*)&Af[s * 8] = v;
  }
  __syncthreads();

  int wv = tid >> 6, ln = tid & 63;
  f32x4 acc[2][2];
#pragma unroll
  for (int i = 0; i < 2; ++i)
#pragma unroll
    for (int j = 0; j < 2; ++j) acc[i][j] = (f32x4){0.f, 0.f, 0.f, 0.f};

#pragma unroll
  for (int kcAll = 0; kcAll < 8; ++kcAll) {
    half8 a0 = *(half8*)&Af[((kcAll * 2 + 0) * 64 + ln) * 8];
    half8 a1 = *(half8*)&Af[((kcAll * 2 + 1) * 64 + ln) * 8];
#pragma unroll
    for (int nt = 0; nt < 2; ++nt) {
      half8 b = *(const half8*)&w2p[((size_t)(kcAll * 8 + wv * 2 + nt) * 64 + ln) * 8];
      acc[0][nt] = MFMA16(a0, b, acc[0][nt]);
      acc[1][nt] = MFMA16(a1, b, acc[1][nt]);
    }
  }
  int lq = ln >> 4, lc = ln & 15;
  float cs[2], cq[2];
#pragma unroll
  for (int nt = 0; nt < 2; ++nt) { cs[nt] = 0.f; cq[nt] = 0.f; }
#pragma unroll
  for (int nt = 0; nt < 2; ++nt) {
    int col = (wv * 2 + nt) * 16 + lc;
    float bias = b2[col];
#pragma unroll
    for (int mt = 0; mt < 2; ++mt) {
      int rbase = row0 + mt * 16 + lq * 4;
#pragma unroll
      for (int rg = 0; rg < 4; ++rg) {
        int row = rbase + rg;
        if (row < N_NODES) {
          float v = acc[mt][nt][rg] + bias;
          if (residual) v += h[(size_t)row * D + col];
          h[(size_t)row * D + col] = v;
          if (writeHH) hh[(size_t)row * D + col] = (_Float16)v;
          cs[nt] += v; cq[nt] += v * v;
        }
      }
    }
  }
#pragma unroll
  for (int nt = 0; nt < 2; ++nt) {
    float v = cs[nt], q = cq[nt];
    v += __shfl_xor(v, 16); v += __shfl_xor(v, 32);
    q += __shfl_xor(q, 16); q += __shfl_xor(q, 32);
    if (lq == 0) {
      int col = (wv * 2 + nt) * 16 + lc;
      atomicAdd(&statHs[slot * 256 + col], v);
      atomicAdd(&statHs[slot * 256 + 128 + col], q);
    }
  }
}

// ---------------------------------------------------------------- fused pool+predict
__global__ __launch_bounds__(256) void k_poolpred(
    const float* __restrict__ h, const int* __restrict__ gstart,
    const float* __restrict__ statHs, const float* __restrict__ gamma,
    const float* __restrict__ beta, const float* __restrict__ pw,
    const float* __restrict__ pb, float* __restrict__ out) {
  __shared__ float sH[256];
  __shared__ float emb[128];
  __shared__ float4 red[256];
  int b = blockIdx.x, tid = threadIdx.x;
  {
    float a = 0.f;
#pragma unroll
    for (int s = 0; s < NSLOT; ++s) a += statHs[s * 256 + tid];
    sH[tid] = a;
  }
  int fl = (tid & 31) << 2, ns = tid >> 5;
  int gs = gstart[b], ge = gstart[b + 1];
  float4 acc = make_float4(0.f, 0.f, 0.f, 0.f);
  for (int n = gs + ns; n < ge; n += 8) {
    float4 v = *(const float4*)&h[(size_t)n * D + fl];
    acc.x += v.x; acc.y += v.y; acc.z += v.z; acc.w += v.w;
  }
  red[tid] = acc;
  __syncthreads();
  if (ns < 4) {
    float4 o = red[tid + 128];
    acc.x += o.x; acc.y += o.y; acc.z += o.z; acc.w += o.w;
    red[tid] = acc;
  }
  __syncthreads();
  if (ns < 2) {
    float4 o = red[tid + 64];
    acc.x += o.x; acc.y += o.y; acc.z += o.z; acc.w += o.w;
    red[tid] = acc;
  }
  __syncthreads();
  if (ns == 0) {
    float4 o = red[tid + 32];
    acc.x += o.x; acc.y += o.y; acc.z += o.z; acc.w += o.w;
    const float invN = 1.0f / (float)N_NODES;
    float inv = (ge > gs) ? 1.0f / (float)(ge - gs) : 0.f;
    float av[4] = {acc.x, acc.y, acc.z, acc.w};
#pragma unroll
    for (int j = 0; j < 4; ++j) {
      int k = fl + j;
      float mu = sH[k] * invN;
      float var = sH[D + k] * invN - mu * mu;
      emb[k] = (ge > gs)
          ? (av[j] * inv - mu) * rsqrtf(var + BN_EPS_F) * gamma[k] + beta[k]
          : 0.f;
    }
  }
  __syncthreads();
  if (tid < NTARGET) {
    float o = pb[tid];
    for (int k = 0; k < D; ++k) o += emb[k] * pw[k * NTARGET + tid];
    out[b * NTARGET + tid] = o;
  }
}

// ---------------------------------------------------------------- launch
extern "C" void kernel_launch(void* const* d_in, const int* in_sizes, int n_in,
                              void* d_out, int out_size, void* d_ws, size_t ws_size,
                              hipStream_t stream) {
  const int* x      = (const int*)d_in[0];
  const int* ei     = (const int*)d_in[1];
  const int* eattr  = (const int*)d_in[2];
  const int* batch  = (const int*)d_in[3];
  const int* aoff   = (const int*)d_in[4];
  const int* boff   = (const int*)d_in[5];
  const float* atab = (const float*)d_in[6];
  const float* btab = (const float*)d_in[7];
  const float* ngam = (const float*)d_in[8];
  const float* nbet = (const float*)d_in[9];
  const float* tptr = (const float*)d_in[10];
  const float* w1   = (const float*)d_in[11];
  const float* b1   = (const float*)d_in[12];
  const float* bng  = (const float*)d_in[13];
  const float* bnb  = (const float*)d_in[14];
  const float* w2   = (const float*)d_in[15];
  const float* b2   = (const float*)d_in[16];
  const float* pw   = (const float*)d_in[17];
  const float* pb   = (const float*)d_in[18];
  float* out = (float*)d_out;

  float* ws = (float*)d_ws;
  const size_t ND = (size_t)N_NODES * D;
  float* h      = ws;                          // ND fp32
  _Float16* hh  = (_Float16*)(ws + 1 * ND);    // ND halfs
  _Float16* xh  = (_Float16*)(ws + 1 * ND + ND / 2); // ND halfs
  _Float16* z1h = (_Float16*)(ws + 2 * ND);    // N*D2 halfs
  float* statAll = ws + 3 * ND;                // 7*NSLOT*(512+256)
  float* stat1sAll = statAll;
  float* statHsAll = statAll + 7 * NSLOT * 512;
  _Float16* bncoefh = (_Float16*)(statHsAll + 7 * NSLOT * 256);  // 256 halfs
  float* comboF = (float*)(bncoefh + 256);
  _Float16* comboh = (_Float16*)comboF;        // 60*128 halfs
  _Float16* w1p = (_Float16*)(comboF + 60 * D / 2);
  _Float16* w2p = w1p + 7 * 32768;
  int* ibuf     = (int*)(w2p + 7 * 32768);
  int* rowptr   = ibuf;                        // N+1
  int* cursor   = rowptr + N_NODES + 1;        // N
  int* deg      = cursor + N_NODES;            // N
  int* payload  = deg + N_NODES;               // E
  int* gstart   = payload + N_EDGES;           // NGRAPH+1
  int* excl     = gstart + NGRAPH + 1;         // N
  int* bsum     = excl + N_NODES;              // 64
  int* hist     = bsum + 64;                   // 64
  int* cursor2  = hist + 64;                   // 64
  int* perm     = cursor2 + 64;                // N

  const int nodeBlocks = (N_NODES * 32 + 255) / 256;
  const int aggrBlocks = (N_NODES * 16 + 255) / 256;  // 3125
  const int edgeThreadBlocks = (N_EDGES + 255) / 256;
  const int gRows32 = (N_NODES + 31) / 32;     // 1563

  (void)hipMemsetAsync(statAll, 0,
                       (size_t)7 * NSLOT * 768 * sizeof(float), stream);
  k_encode<<<nodeBlocks, 256, 0, stream>>>(x, aoff, atab, h, hh, deg);
  k_setup<<<451, 256, 0, stream>>>(w1, w2, w1p, w2p, boff, btab, comboh,
                                   batch, gstart, hist, bncoefh);
  k_degree<<<edgeThreadBlocks, 256, 0, stream>>>(ei, deg);
  k_scan1<<<NSB, 1024, 0, stream>>>(deg, excl, bsum, hist);
  k_scan2<<<1, 64, 0, stream>>>(bsum, hist, cursor2);
  k_scan3<<<(N_NODES + 256) / 256, 256, 0, stream>>>(excl, bsum, deg, cursor2,
                                                     rowptr, cursor, perm);
  k_scatter<<<edgeThreadBlocks, 256, 0, stream>>>(ei, eattr, cursor, payload);

  for (int l = 0; l < 7; ++l) {
    if (l > 0)
      k_bncoef<<<1, 128, 0, stream>>>(statHsAll + (size_t)(l - 1) * NSLOT * 256,
                                      ngam + l * D, nbet + l * D, bncoefh);
    k_aggrx<<<aggrBlocks, 256, 0, stream>>>(
        hh, rowptr, payload, comboh, perm, tptr, l, bncoefh,
        l == 0 ? -65504.f : 0.f, xh);
    k_gemm1<<<gRows32, 256, 0, stream>>>(xh, w1p + (size_t)l * 32768,
                                         b1 + l * D2, z1h,
                                         stat1sAll + (size_t)l * NSLOT * 512);
    k_gemm2<<<gRows32, 256, 0, stream>>>(
        z1h, stat1sAll + (size_t)l * NSLOT * 512, bng + l * D2, bnb + l * D2,
        w2p + (size_t)l * 32768, b2 + l * D, h, hh, l > 0 ? 1 : 0,
        l < 6 ? 1 : 0, statHsAll + (size_t)l * NSLOT * 256);
  }

  k_poolpred<<<NGRAPH, 256, 0, stream>>>(h, gstart,
                                         statHsAll + (size_t)6 * NSLOT * 256,
                                         ngam, nbet, pw, pb, out);
}